// Round 1
// baseline (672.692 us; speedup 1.0000x reference)
//
#include <hip/hip_runtime.h>

// Problem constants: B=8, C=256, H=W=32, NH=8, DK=160, DV=64, DKH=20, DVH=8
constexpr float QSCALE = 0.22360679774997896f; // 1/sqrt(20)

// ---------------- kqv 1x1 conv as GEMM: (384x256) @ (256x1024) ----------------
__global__ __launch_bounds__(256) void kqv_gemm_kernel(
    const float* __restrict__ X, const float* __restrict__ W,
    const float* __restrict__ bias, float* __restrict__ out)
{
    const int b   = blockIdx.z;
    const int s0  = blockIdx.x * 64;
    const int oc0 = blockIdx.y * 64;
    __shared__ float As[16][64];
    __shared__ float Bs[16][68];
    const int tid = threadIdx.x;
    const int tx = tid & 15, ty = tid >> 4;
    float acc[4][4] = {};
    const float* Xb = X + (size_t)b * 262144;

    for (int k0 = 0; k0 < 256; k0 += 16) {
        {
            int r = tid >> 2, c4 = (tid & 3) * 4;
            float4 a = *(const float4*)&W[(oc0 + r) * 256 + k0 + c4];
            As[c4 + 0][r] = a.x; As[c4 + 1][r] = a.y;
            As[c4 + 2][r] = a.z; As[c4 + 3][r] = a.w;
        }
        {
            int r = tid >> 4, c4 = (tid & 15) * 4;
            float4 v = *(const float4*)&Xb[(size_t)(k0 + r) * 1024 + s0 + c4];
            *(float4*)&Bs[r][c4] = v;
        }
        __syncthreads();
        #pragma unroll
        for (int kk = 0; kk < 16; ++kk) {
            float4 a  = *(const float4*)&As[kk][ty * 4];
            float4 bv = *(const float4*)&Bs[kk][tx * 4];
            float av[4] = {a.x, a.y, a.z, a.w};
            float bb[4] = {bv.x, bv.y, bv.z, bv.w};
            #pragma unroll
            for (int u = 0; u < 4; ++u)
                #pragma unroll
                for (int v = 0; v < 4; ++v)
                    acc[u][v] += av[u] * bb[v];
        }
        __syncthreads();
    }
    #pragma unroll
    for (int u = 0; u < 4; ++u) {
        int oc = oc0 + ty * 4 + u;
        float bb = bias[oc];
        float sc = (oc >= 160 && oc < 320) ? QSCALE : 1.0f;
        float4 res;
        res.x = (acc[u][0] + bb) * sc;
        res.y = (acc[u][1] + bb) * sc;
        res.z = (acc[u][2] + bb) * sc;
        res.w = (acc[u][3] + bb) * sc;
        *(float4*)&out[(size_t)b * 393216 + (size_t)oc * 1024 + s0 + tx * 4] = res;
    }
}

// ---------------- conv_out 3x3 as implicit GEMM: (192x2304) @ im2col(2304x1024) ----
__global__ __launch_bounds__(256) void conv3x3_gemm_kernel(
    const float* __restrict__ X, const float* __restrict__ W,
    const float* __restrict__ bias, float* __restrict__ out)
{
    const int b   = blockIdx.z;
    const int s0  = blockIdx.x * 64;
    const int oc0 = blockIdx.y * 64;
    __shared__ float As[16][64];
    __shared__ float Bs[16][68];
    const int tid = threadIdx.x;
    const int tx = tid & 15, ty = tid >> 4;
    float acc[4][4] = {};
    const float* Xb = X + (size_t)b * 262144;

    for (int k0 = 0; k0 < 2304; k0 += 16) {
        {
            int r = tid >> 2, c4 = (tid & 3) * 4;
            float4 a = *(const float4*)&W[(size_t)(oc0 + r) * 2304 + k0 + c4];
            As[c4 + 0][r] = a.x; As[c4 + 1][r] = a.y;
            As[c4 + 2][r] = a.z; As[c4 + 3][r] = a.w;
        }
        {
            int r = tid >> 4, c4b = (tid & 15) * 4;
            int k  = k0 + r;
            int cc = k / 9;
            int rr = k - cc * 9;
            int ky = rr / 3;
            int kx = rr - ky * 3;
            const float* src = Xb + (size_t)cc * 1024;
            #pragma unroll
            for (int u = 0; u < 4; ++u) {
                int s = s0 + c4b + u;
                int y = s >> 5, x = s & 31;
                int yy = y + ky - 1, xx = x + kx - 1;
                float v = 0.0f;
                if ((unsigned)yy < 32u && (unsigned)xx < 32u) v = src[yy * 32 + xx];
                Bs[r][c4b + u] = v;
            }
        }
        __syncthreads();
        #pragma unroll
        for (int kk = 0; kk < 16; ++kk) {
            float4 a  = *(const float4*)&As[kk][ty * 4];
            float4 bv = *(const float4*)&Bs[kk][tx * 4];
            float av[4] = {a.x, a.y, a.z, a.w};
            float bb[4] = {bv.x, bv.y, bv.z, bv.w};
            #pragma unroll
            for (int u = 0; u < 4; ++u)
                #pragma unroll
                for (int v = 0; v < 4; ++v)
                    acc[u][v] += av[u] * bb[v];
        }
        __syncthreads();
    }
    #pragma unroll
    for (int u = 0; u < 4; ++u) {
        int oc = oc0 + ty * 4 + u;
        float bb = bias[oc];
        float4 res;
        res.x = acc[u][0] + bb;
        res.y = acc[u][1] + bb;
        res.z = acc[u][2] + bb;
        res.w = acc[u][3] + bb;
        *(float4*)&out[(size_t)b * 262144 + (size_t)oc * 1024 + s0 + tx * 4] = res;
    }
}

// ---------------- head-sum of q: qsum[b][s][d] = sum_n q[b][n*20480 + s*20 + d] ----
__global__ void qsum_kernel(const float* __restrict__ kqv, float* __restrict__ qsum)
{
    int idx = blockIdx.x * 256 + threadIdx.x;   // 8 * 20480 = 163840
    int b = idx / 20480, t = idx - b * 20480;
    const float* qb = kqv + (size_t)b * 393216 + 163840 + t;
    float s = 0.0f;
    #pragma unroll
    for (int n = 0; n < 8; ++n) s += qb[(size_t)n * 20480];
    qsum[idx] = s;
}

// ---------------- rel logits (relative coords): R*_rel[b][.][m] -------------------
__global__ void rel_kernel(const float* __restrict__ qsum,
    const float* __restrict__ rel_h, const float* __restrict__ rel_w,
    float* __restrict__ Rh, float* __restrict__ Rw)
{
    int idx = blockIdx.x * 256 + threadIdx.x;   // 8 * 1024 * 63 = 516096
    int b = idx / 64512, rem = idx - b * 64512;
    int s = rem / 63, mm = rem - s * 63;
    int y = s >> 5, x = s & 31;
    const float* qrow = qsum + (size_t)b * 20480 + s * 20;
    const float* rh = rel_h + mm * 20;
    const float* rw = rel_w + mm * 20;
    float sh = 0.0f, sw = 0.0f;
    #pragma unroll
    for (int d = 0; d < 20; ++d) {
        float qv = qrow[d];
        sh += qv * rh[d];
        sw += qv * rw[d];
    }
    Rw[(size_t)b * 64512 + s * 63 + mm] = sw;                 // [b][y*32+x][m]
    Rh[(size_t)b * 64512 + (x * 32 + y) * 63 + mm] = sh;      // [b][x*32+y][m]
}

// ---------------- fused attention: one thread per query row -----------------------
__global__ __launch_bounds__(256) void attn_kernel(
    const float* __restrict__ kqv, const float* __restrict__ Rh,
    const float* __restrict__ Rw, float* __restrict__ attnout)
{
    const int bn = blockIdx.y;            // 0..63
    const int b = bn >> 3, n = bn & 7;
    const int i = blockIdx.x * 256 + threadIdx.x;   // query row 0..1023
    const int y1 = i >> 5, x1 = i & 31;
    __shared__ float relsh[64][256];      // [y2 | 32+x2][row-thread] : 64 KB

    {
        const float* rhrow = Rh + (size_t)b * 64512 + (x1 * 32 + y1) * 63;
        const float* rwrow = Rw + (size_t)b * 64512 + (y1 * 32 + x1) * 63;
        #pragma unroll
        for (int y2 = 0; y2 < 32; ++y2)
            relsh[y2][threadIdx.x] = rhrow[31 + y2 - y1];
        #pragma unroll
        for (int x2 = 0; x2 < 32; ++x2)
            relsh[32 + x2][threadIdx.x] = rwrow[31 + x2 - x1];
    }
    __syncthreads();

    const float* base = kqv + (size_t)b * 393216;
    const float* qrow = base + 163840 + n * 20480 + i * 20;
    float q[20];
    #pragma unroll
    for (int d0 = 0; d0 < 20; d0 += 4) {
        float4 t = *(const float4*)&qrow[d0];
        q[d0] = t.x; q[d0 + 1] = t.y; q[d0 + 2] = t.z; q[d0 + 3] = t.w;
    }
    const float* Kb = base + n * 20480;
    const float* Vb = base + 327680 + n * 8192;

    float m = -1e30f, lsum = 0.0f;
    float acc[8] = {};

    #pragma unroll 2
    for (int j = 0; j < 1024; ++j) {
        const float* krow = Kb + j * 20;
        float4 k0 = *(const float4*)&krow[0];
        float4 k1 = *(const float4*)&krow[4];
        float4 k2 = *(const float4*)&krow[8];
        float4 k3 = *(const float4*)&krow[12];
        float4 k4 = *(const float4*)&krow[16];
        float d0 = q[0]  * k0.x + q[1]  * k0.y + q[2]  * k0.z + q[3]  * k0.w;
        float d1 = q[4]  * k1.x + q[5]  * k1.y + q[6]  * k1.z + q[7]  * k1.w;
        float d2 = q[8]  * k2.x + q[9]  * k2.y + q[10] * k2.z + q[11] * k2.w;
        float d3 = q[12] * k3.x + q[13] * k3.y + q[14] * k3.z + q[15] * k3.w;
        float d4 = q[16] * k4.x + q[17] * k4.y + q[18] * k4.z + q[19] * k4.w;
        float logit = ((d0 + d1) + (d2 + d3)) + d4;
        logit += relsh[j >> 5][threadIdx.x] + relsh[32 + (j & 31)][threadIdx.x];

        if (logit > m) {
            float sc = __expf(m - logit);
            lsum *= sc;
            #pragma unroll
            for (int e = 0; e < 8; ++e) acc[e] *= sc;
            m = logit;
        }
        float p = __expf(logit - m);
        lsum += p;
        float4 v0 = *(const float4*)&Vb[j * 8];
        float4 v1 = *(const float4*)&Vb[j * 8 + 4];
        acc[0] += p * v0.x; acc[1] += p * v0.y; acc[2] += p * v0.z; acc[3] += p * v0.w;
        acc[4] += p * v1.x; acc[5] += p * v1.y; acc[6] += p * v1.z; acc[7] += p * v1.w;
    }

    float inv = 1.0f / lsum;
    float4 o0 = {acc[0] * inv, acc[1] * inv, acc[2] * inv, acc[3] * inv};
    float4 o1 = {acc[4] * inv, acc[5] * inv, acc[6] * inv, acc[7] * inv};
    float* outp = attnout + (size_t)b * 65536 + n * 8192 + i * 8;
    *(float4*)&outp[0] = o0;
    *(float4*)&outp[4] = o1;
}

// ---------------- attn 1x1 conv (64->64) into output channels 192..255 ------------
__global__ __launch_bounds__(256) void attn_out_conv_kernel(
    const float* __restrict__ attn, const float* __restrict__ W,
    const float* __restrict__ bias, float* __restrict__ out)
{
    const int b  = blockIdx.z;
    const int oc = blockIdx.y;
    const int s  = blockIdx.x * 256 + threadIdx.x;
    const float* ab = attn + (size_t)b * 65536;
    float sum = bias[oc];
    #pragma unroll
    for (int c = 0; c < 64; ++c)
        sum += W[oc * 64 + c] * ab[(size_t)c * 1024 + s];
    out[(size_t)b * 262144 + (size_t)(192 + oc) * 1024 + s] = sum;
}

extern "C" void kernel_launch(void* const* d_in, const int* in_sizes, int n_in,
                              void* d_out, int out_size, void* d_ws, size_t ws_size,
                              hipStream_t stream)
{
    const float* x          = (const float*)d_in[0];
    const float* kqv_w      = (const float*)d_in[1];
    const float* kqv_b      = (const float*)d_in[2];
    const float* conv_out_w = (const float*)d_in[3];
    const float* conv_out_b = (const float*)d_in[4];
    const float* attn_w     = (const float*)d_in[5];
    const float* attn_b     = (const float*)d_in[6];
    const float* rel_h      = (const float*)d_in[7];
    const float* rel_w      = (const float*)d_in[8];
    float* out = (float*)d_out;
    float* ws  = (float*)d_ws;

    float* ws_kqv  = ws;                   // 8*384*1024      = 3145728 f32
    float* ws_qsum = ws_kqv + 3145728;     // 8*1024*20       = 163840
    float* ws_rw   = ws_qsum + 163840;     // 8*1024*63       = 516096
    float* ws_rh   = ws_rw + 516096;       // 8*1024*63       = 516096
    float* ws_attn = ws_rh + 516096;       // 8*64*1024       = 524288
    // total ~19.5 MB of d_ws

    kqv_gemm_kernel<<<dim3(16, 6, 8), 256, 0, stream>>>(x, kqv_w, kqv_b, ws_kqv);
    qsum_kernel<<<640, 256, 0, stream>>>(ws_kqv, ws_qsum);
    rel_kernel<<<2016, 256, 0, stream>>>(ws_qsum, rel_h, rel_w, ws_rh, ws_rw);
    attn_kernel<<<dim3(4, 64), 256, 0, stream>>>(ws_kqv, ws_rh, ws_rw, ws_attn);
    attn_out_conv_kernel<<<dim3(4, 64, 8), 256, 0, stream>>>(ws_attn, attn_w, attn_b, out);
    conv3x3_gemm_kernel<<<dim3(16, 3, 8), 256, 0, stream>>>(x, conv_out_w, conv_out_b, out);
}

// Round 2
// 397.276 us; speedup vs baseline: 1.6933x; 1.6933x over previous
//
#include <hip/hip_runtime.h>

// Problem constants: B=8, C=256, H=W=32, NH=8, DK=160, DV=64, DKH=20, DVH=8
constexpr float QSCALE = 0.22360679774997896f; // 1/sqrt(20)
constexpr int NCHUNK = 4;                      // split-KV chunks of 256 keys
constexpr int CHUNK  = 1024 / NCHUNK;

// ---------------- kqv 1x1 conv as GEMM: (384x256) @ (256x1024) ----------------
__global__ __launch_bounds__(256) void kqv_gemm_kernel(
    const float* __restrict__ X, const float* __restrict__ W,
    const float* __restrict__ bias, float* __restrict__ out)
{
    const int b   = blockIdx.z;
    const int s0  = blockIdx.x * 64;
    const int oc0 = blockIdx.y * 64;
    __shared__ float As[16][64];
    __shared__ float Bs[16][68];
    const int tid = threadIdx.x;
    const int tx = tid & 15, ty = tid >> 4;
    float acc[4][4] = {};
    const float* Xb = X + (size_t)b * 262144;

    for (int k0 = 0; k0 < 256; k0 += 16) {
        {
            int r = tid >> 2, c4 = (tid & 3) * 4;
            float4 a = *(const float4*)&W[(oc0 + r) * 256 + k0 + c4];
            As[c4 + 0][r] = a.x; As[c4 + 1][r] = a.y;
            As[c4 + 2][r] = a.z; As[c4 + 3][r] = a.w;
        }
        {
            int r = tid >> 4, c4 = (tid & 15) * 4;
            float4 v = *(const float4*)&Xb[(size_t)(k0 + r) * 1024 + s0 + c4];
            *(float4*)&Bs[r][c4] = v;
        }
        __syncthreads();
        #pragma unroll
        for (int kk = 0; kk < 16; ++kk) {
            float4 a  = *(const float4*)&As[kk][ty * 4];
            float4 bv = *(const float4*)&Bs[kk][tx * 4];
            float av[4] = {a.x, a.y, a.z, a.w};
            float bb[4] = {bv.x, bv.y, bv.z, bv.w};
            #pragma unroll
            for (int u = 0; u < 4; ++u)
                #pragma unroll
                for (int v = 0; v < 4; ++v)
                    acc[u][v] += av[u] * bb[v];
        }
        __syncthreads();
    }
    #pragma unroll
    for (int u = 0; u < 4; ++u) {
        int oc = oc0 + ty * 4 + u;
        float bb = bias[oc];
        float sc = (oc >= 160 && oc < 320) ? QSCALE : 1.0f;
        float4 res;
        res.x = (acc[u][0] + bb) * sc;
        res.y = (acc[u][1] + bb) * sc;
        res.z = (acc[u][2] + bb) * sc;
        res.w = (acc[u][3] + bb) * sc;
        *(float4*)&out[(size_t)b * 393216 + (size_t)oc * 1024 + s0 + tx * 4] = res;
    }
}

// ---------------- conv_out 3x3 as implicit GEMM: (192x2304) @ im2col(2304x1024) ----
__global__ __launch_bounds__(256) void conv3x3_gemm_kernel(
    const float* __restrict__ X, const float* __restrict__ W,
    const float* __restrict__ bias, float* __restrict__ out)
{
    const int b   = blockIdx.z;
    const int s0  = blockIdx.x * 64;
    const int oc0 = blockIdx.y * 64;
    __shared__ float As[16][64];
    __shared__ float Bs[16][68];
    const int tid = threadIdx.x;
    const int tx = tid & 15, ty = tid >> 4;
    float acc[4][4] = {};
    const float* Xb = X + (size_t)b * 262144;

    for (int k0 = 0; k0 < 2304; k0 += 16) {
        {
            int r = tid >> 2, c4 = (tid & 3) * 4;
            float4 a = *(const float4*)&W[(size_t)(oc0 + r) * 2304 + k0 + c4];
            As[c4 + 0][r] = a.x; As[c4 + 1][r] = a.y;
            As[c4 + 2][r] = a.z; As[c4 + 3][r] = a.w;
        }
        {
            int r = tid >> 4, c4b = (tid & 15) * 4;
            int k  = k0 + r;
            int cc = k / 9;
            int rr = k - cc * 9;
            int ky = rr / 3;
            int kx = rr - ky * 3;
            const float* src = Xb + (size_t)cc * 1024;
            #pragma unroll
            for (int u = 0; u < 4; ++u) {
                int s = s0 + c4b + u;
                int y = s >> 5, x = s & 31;
                int yy = y + ky - 1, xx = x + kx - 1;
                float v = 0.0f;
                if ((unsigned)yy < 32u && (unsigned)xx < 32u) v = src[yy * 32 + xx];
                Bs[r][c4b + u] = v;
            }
        }
        __syncthreads();
        #pragma unroll
        for (int kk = 0; kk < 16; ++kk) {
            float4 a  = *(const float4*)&As[kk][ty * 4];
            float4 bv = *(const float4*)&Bs[kk][tx * 4];
            float av[4] = {a.x, a.y, a.z, a.w};
            float bb[4] = {bv.x, bv.y, bv.z, bv.w};
            #pragma unroll
            for (int u = 0; u < 4; ++u)
                #pragma unroll
                for (int v = 0; v < 4; ++v)
                    acc[u][v] += av[u] * bb[v];
        }
        __syncthreads();
    }
    #pragma unroll
    for (int u = 0; u < 4; ++u) {
        int oc = oc0 + ty * 4 + u;
        float bb = bias[oc];
        float4 res;
        res.x = acc[u][0] + bb;
        res.y = acc[u][1] + bb;
        res.z = acc[u][2] + bb;
        res.w = acc[u][3] + bb;
        *(float4*)&out[(size_t)b * 262144 + (size_t)oc * 1024 + s0 + tx * 4] = res;
    }
}

// ---------------- head-sum of q: qsum[b][s][d] = sum_n q[b][n*20480 + s*20 + d] ----
__global__ void qsum_kernel(const float* __restrict__ kqv, float* __restrict__ qsum)
{
    int idx = blockIdx.x * 256 + threadIdx.x;   // 8 * 20480 = 163840
    int b = idx / 20480, t = idx - b * 20480;
    const float* qb = kqv + (size_t)b * 393216 + 163840 + t;
    float s = 0.0f;
    #pragma unroll
    for (int n = 0; n < 8; ++n) s += qb[(size_t)n * 20480];
    qsum[idx] = s;
}

// ---------------- rel logits (relative coords): R*_rel[b][.][m] -------------------
__global__ void rel_kernel(const float* __restrict__ qsum,
    const float* __restrict__ rel_h, const float* __restrict__ rel_w,
    float* __restrict__ Rh, float* __restrict__ Rw)
{
    int idx = blockIdx.x * 256 + threadIdx.x;   // 8 * 1024 * 63 = 516096
    int b = idx / 64512, rem = idx - b * 64512;
    int s = rem / 63, mm = rem - s * 63;
    int y = s >> 5, x = s & 31;
    const float* qrow = qsum + (size_t)b * 20480 + s * 20;
    const float* rh = rel_h + mm * 20;
    const float* rw = rel_w + mm * 20;
    float sh = 0.0f, sw = 0.0f;
    #pragma unroll
    for (int d = 0; d < 20; ++d) {
        float qv = qrow[d];
        sh += qv * rh[d];
        sw += qv * rw[d];
    }
    Rw[(size_t)b * 64512 + s * 63 + mm] = sw;                 // [b][y*32+x][m]
    Rh[(size_t)b * 64512 + (x * 32 + y) * 63 + mm] = sh;      // [b][x*32+y][m]
}

// ---------------- split-KV attention partials -------------------------------------
// grid: (4 row-tiles, 64 bn, NCHUNK chunks); one thread = one query row x one chunk
__global__ __launch_bounds__(256, 4) void attn_part_kernel(
    const float* __restrict__ kqv, const float* __restrict__ Rh,
    const float* __restrict__ Rw, float* __restrict__ part)
{
    const int bn = blockIdx.y;            // 0..63
    const int b = bn >> 3, n = bn & 7;
    const int chunk = blockIdx.z;         // 0..NCHUNK-1
    const int i = blockIdx.x * 256 + threadIdx.x;   // query row 0..1023
    const int y1 = i >> 5, x1 = i & 31;

    const float* base = kqv + (size_t)b * 393216;
    const float* qrow = base + 163840 + n * 20480 + i * 20;
    float q[20];
    #pragma unroll
    for (int d0 = 0; d0 < 20; d0 += 4) {
        float4 t = *(const float4*)&qrow[d0];
        q[d0] = t.x; q[d0 + 1] = t.y; q[d0 + 2] = t.z; q[d0 + 3] = t.w;
    }

    // per-thread relative-logit rows (registers, statically indexed)
    float Rwreg[32];
    const float* rwrow = Rw + (size_t)b * 64512 + i * 63;            // (y1*32+x1)==i
    #pragma unroll
    for (int x2 = 0; x2 < 32; ++x2) Rwreg[x2] = rwrow[31 + x2 - x1];
    const float* rhrow = Rh + (size_t)b * 64512 + (x1 * 32 + y1) * 63;
    const int y2base = chunk * (CHUNK / 32);

    const float* Kb = base + n * 20480 + chunk * CHUNK * 20;
    const float* Vb = base + 327680 + n * 8192 + chunk * CHUNK * 8;

    float m = -1e30f, lsum = 0.0f;
    float acc[8] = {};

    for (int t = 0; t < CHUNK / 32; ++t) {
        float rh = rhrow[31 + y2base + t - y1];
        const float* krow = Kb + t * 32 * 20;
        const float* vrow = Vb + t * 32 * 8;
        #pragma unroll
        for (int x2 = 0; x2 < 32; ++x2) {
            float4 k0 = *(const float4*)&krow[x2 * 20 + 0];
            float4 k1 = *(const float4*)&krow[x2 * 20 + 4];
            float4 k2 = *(const float4*)&krow[x2 * 20 + 8];
            float4 k3 = *(const float4*)&krow[x2 * 20 + 12];
            float4 k4 = *(const float4*)&krow[x2 * 20 + 16];
            float d0 = q[0]  * k0.x + q[1]  * k0.y + q[2]  * k0.z + q[3]  * k0.w;
            float d1 = q[4]  * k1.x + q[5]  * k1.y + q[6]  * k1.z + q[7]  * k1.w;
            float d2 = q[8]  * k2.x + q[9]  * k2.y + q[10] * k2.z + q[11] * k2.w;
            float d3 = q[12] * k3.x + q[13] * k3.y + q[14] * k3.z + q[15] * k3.w;
            float d4 = q[16] * k4.x + q[17] * k4.y + q[18] * k4.z + q[19] * k4.w;
            float logit = ((d0 + d1) + (d2 + d3)) + d4 + rh + Rwreg[x2];

            if (logit > m) {
                float sc = __expf(m - logit);
                lsum *= sc;
                #pragma unroll
                for (int e = 0; e < 8; ++e) acc[e] *= sc;
                m = logit;
            }
            float p = __expf(logit - m);
            lsum += p;
            float4 v0 = *(const float4*)&vrow[x2 * 8];
            float4 v1 = *(const float4*)&vrow[x2 * 8 + 4];
            acc[0] += p * v0.x; acc[1] += p * v0.y; acc[2] += p * v0.z; acc[3] += p * v0.w;
            acc[4] += p * v1.x; acc[5] += p * v1.y; acc[6] += p * v1.z; acc[7] += p * v1.w;
        }
    }

    // SoA partials: part[(chunk*10 + field)*65536 + bn*1024 + i]
    const int ridx = bn * 1024 + i;
    float* pp = part + (size_t)chunk * 10 * 65536 + ridx;
    pp[0]         = m;
    pp[65536]     = lsum;
    #pragma unroll
    for (int e = 0; e < 8; ++e) pp[(size_t)(2 + e) * 65536] = acc[e];
}

// ---------------- combine split-KV partials ---------------------------------------
__global__ __launch_bounds__(256) void attn_combine_kernel(
    const float* __restrict__ part, float* __restrict__ attnout)
{
    const int idx = blockIdx.x * 256 + threadIdx.x;   // bn*1024 + i, 0..65535
    float mc[NCHUNK];
    float M = -1e30f;
    #pragma unroll
    for (int c = 0; c < NCHUNK; ++c) {
        mc[c] = part[(size_t)(c * 10) * 65536 + idx];
        M = fmaxf(M, mc[c]);
    }
    float l = 0.0f, acc[8] = {};
    #pragma unroll
    for (int c = 0; c < NCHUNK; ++c) {
        float w = __expf(mc[c] - M);
        const float* pp = part + (size_t)(c * 10) * 65536 + idx;
        l += w * pp[65536];
        #pragma unroll
        for (int e = 0; e < 8; ++e) acc[e] += w * pp[(size_t)(2 + e) * 65536];
    }
    float inv = 1.0f / l;
    float4 o0 = {acc[0] * inv, acc[1] * inv, acc[2] * inv, acc[3] * inv};
    float4 o1 = {acc[4] * inv, acc[5] * inv, acc[6] * inv, acc[7] * inv};
    float* outp = attnout + (size_t)idx * 8;          // == b*65536 + n*8192 + i*8
    *(float4*)&outp[0] = o0;
    *(float4*)&outp[4] = o1;
}

// ---------------- attn 1x1 conv (64->64) into output channels 192..255 ------------
__global__ __launch_bounds__(256) void attn_out_conv_kernel(
    const float* __restrict__ attn, const float* __restrict__ W,
    const float* __restrict__ bias, float* __restrict__ out)
{
    const int b  = blockIdx.z;
    const int oc = blockIdx.y;
    const int s  = blockIdx.x * 256 + threadIdx.x;
    const float* ab = attn + (size_t)b * 65536;
    float sum = bias[oc];
    #pragma unroll
    for (int c = 0; c < 64; ++c)
        sum += W[oc * 64 + c] * ab[(size_t)c * 1024 + s];
    out[(size_t)b * 262144 + (size_t)(192 + oc) * 1024 + s] = sum;
}

extern "C" void kernel_launch(void* const* d_in, const int* in_sizes, int n_in,
                              void* d_out, int out_size, void* d_ws, size_t ws_size,
                              hipStream_t stream)
{
    const float* x          = (const float*)d_in[0];
    const float* kqv_w      = (const float*)d_in[1];
    const float* kqv_b      = (const float*)d_in[2];
    const float* conv_out_w = (const float*)d_in[3];
    const float* conv_out_b = (const float*)d_in[4];
    const float* attn_w     = (const float*)d_in[5];
    const float* attn_b     = (const float*)d_in[6];
    const float* rel_h      = (const float*)d_in[7];
    const float* rel_w      = (const float*)d_in[8];
    float* out = (float*)d_out;
    float* ws  = (float*)d_ws;

    float* ws_kqv  = ws;                   // 8*384*1024      = 3145728 f32
    float* ws_qsum = ws_kqv + 3145728;     // 8*1024*20       = 163840
    float* ws_rw   = ws_qsum + 163840;     // 8*1024*63       = 516096
    float* ws_rh   = ws_rw + 516096;       // 8*1024*63       = 516096
    float* ws_attn = ws_rh + 516096;       // 8*64*1024       = 524288
    float* ws_part = ws_attn + 524288;     // NCHUNK*10*65536 = 2621440
    // total ~30 MB of d_ws

    kqv_gemm_kernel<<<dim3(16, 6, 8), 256, 0, stream>>>(x, kqv_w, kqv_b, ws_kqv);
    qsum_kernel<<<640, 256, 0, stream>>>(ws_kqv, ws_qsum);
    rel_kernel<<<2016, 256, 0, stream>>>(ws_qsum, rel_h, rel_w, ws_rh, ws_rw);
    attn_part_kernel<<<dim3(4, 64, NCHUNK), 256, 0, stream>>>(ws_kqv, ws_rh, ws_rw, ws_part);
    attn_combine_kernel<<<256, 256, 0, stream>>>(ws_part, ws_attn);
    attn_out_conv_kernel<<<dim3(4, 64, 8), 256, 0, stream>>>(ws_attn, attn_w, attn_b, out);
    conv3x3_gemm_kernel<<<dim3(16, 3, 8), 256, 0, stream>>>(x, conv_out_w, conv_out_b, out);
}

// Round 3
// 227.491 us; speedup vs baseline: 2.9570x; 1.7463x over previous
//
#include <hip/hip_runtime.h>

// Problem constants: B=8, C=256, H=W=32, NH=8, DK=160, DV=64, DKH=20, DVH=8
constexpr float QSCALE = 0.22360679774997896f; // 1/sqrt(20)
constexpr int NCHUNK = 4;                      // split-KV chunks of 256 keys
constexpr int CHUNK  = 1024 / NCHUNK;

typedef __attribute__((ext_vector_type(8))) short bf16x8;
typedef __attribute__((ext_vector_type(4))) float f32x4;

__device__ __forceinline__ unsigned short f2bf(float f) {
    unsigned u = __float_as_uint(f);
    u = (u + 0x7FFFu + ((u >> 16) & 1u)) >> 16;   // RNE
    return (unsigned short)u;
}

// ---- pack x (f32 NCHW) -> Xt bf16 [b][(y+1)*34+(x+1)][256ch], zero-padded halo ----
__global__ __launch_bounds__(256) void pack_xt_kernel(
    const float* __restrict__ X, unsigned short* __restrict__ Xt)
{
    int t = blockIdx.x * 256 + threadIdx.x;        // 8*1156*32 = 295936
    int b = t / 36992, rem = t - b * 36992;
    int spad = rem >> 5, cc = rem & 31;
    int yp = spad / 34, xp = spad - yp * 34;
    bf16x8 v = {};
    if (yp >= 1 && yp <= 32 && xp >= 1 && xp <= 32) {
        const float* src = X + (size_t)b * 262144 + (size_t)(cc * 8) * 1024
                             + (yp - 1) * 32 + (xp - 1);
        #pragma unroll
        for (int j = 0; j < 8; ++j) v[j] = (short)f2bf(src[(size_t)j * 1024]);
    }
    *(bf16x8*)&Xt[((size_t)b * 1156 + spad) * 256 + cc * 8] = v;
}

// ---- pack conv_out_w (OIHW f32) -> fragment-order bf16, K reordered k'=r*256+c ----
// Wp[ot(3)][ks(72)][rb(4)][lane(64)][8]
__global__ __launch_bounds__(256) void pack_wconv_kernel(
    const float* __restrict__ W, unsigned short* __restrict__ Wp)
{
    int t = blockIdx.x * 256 + threadIdx.x;        // 3*72*4*64 = 55296
    int l = t & 63;
    int rb = (t >> 6) & 3;
    int ks = (t >> 8) % 72;
    int ot = t / 18432;
    int oc = ot * 64 + rb * 16 + (l & 15);
    int kbase = ks * 32 + (l >> 4) * 8;
    bf16x8 v;
    #pragma unroll
    for (int j = 0; j < 8; ++j) {
        int kp = kbase + j;
        int r = kp >> 8, c = kp & 255;             // k' = r*256 + c
        v[j] = (short)f2bf(W[((size_t)oc * 256 + c) * 9 + r]);
    }
    *(bf16x8*)&Wp[(size_t)t * 8] = v;
}

// ---- pack kqv_w -> fragment-order bf16 (QSCALE folded into q rows) ----
// Wq[ot(6)][ks(8)][rb(4)][lane(64)][8]
__global__ __launch_bounds__(256) void pack_wkqv_kernel(
    const float* __restrict__ W, unsigned short* __restrict__ Wq)
{
    int t = blockIdx.x * 256 + threadIdx.x;        // 6*8*4*64 = 12288
    int l = t & 63;
    int rb = (t >> 6) & 3;
    int ks = (t >> 8) & 7;
    int ot = t / 2048;
    int oc = ot * 64 + rb * 16 + (l & 15);
    float sc = (oc >= 160 && oc < 320) ? QSCALE : 1.0f;
    int kbase = ks * 32 + (l >> 4) * 8;
    bf16x8 v;
    #pragma unroll
    for (int j = 0; j < 8; ++j)
        v[j] = (short)f2bf(W[(size_t)oc * 256 + kbase + j] * sc);
    *(bf16x8*)&Wq[(size_t)t * 8] = v;
}

// ---- conv_out 3x3 as bf16 MFMA implicit GEMM (LDS-free, direct fragments) ----
__global__ __launch_bounds__(256) void mfma_conv3x3_kernel(
    const unsigned short* __restrict__ Wp, const unsigned short* __restrict__ Xt,
    const float* __restrict__ bias, float* __restrict__ out)
{
    const int b  = blockIdx.z;
    const int ot = blockIdx.y;                     // 0..2
    const int s0 = blockIdx.x * 64;
    const int tid = threadIdx.x;
    const int lane = tid & 63, w = tid >> 6;
    const int wr = w >> 1, wc = w & 1;
    const int kc = lane >> 4, ln = lane & 15;

    const size_t aoff0 = ((size_t)(ot * 288 + wr * 2 + 0) * 64 + lane) * 8;
    const size_t aoff1 = ((size_t)(ot * 288 + wr * 2 + 1) * 64 + lane) * 8;

    int s_a = s0 + wc * 32 + ln;
    int base0 = ((b * 1156 + ((s_a >> 5) + 1) * 34 + ((s_a & 31) + 1)) * 256 + kc * 8);
    int s_b2 = s_a + 16;
    int base1 = ((b * 1156 + ((s_b2 >> 5) + 1) * 34 + ((s_b2 & 31) + 1)) * 256 + kc * 8);

    f32x4 acc00 = {}, acc01 = {}, acc10 = {}, acc11 = {};

    #pragma unroll 2
    for (int ks = 0; ks < 72; ++ks) {
        int r = ks >> 3;
        int ky = r / 3, kx = r - ky * 3;
        int uoff = ((ky - 1) * 34 + (kx - 1)) * 256 + (ks & 7) * 32;
        bf16x8 a0 = *(const bf16x8*)&Wp[aoff0 + (size_t)ks * 2048];
        bf16x8 a1 = *(const bf16x8*)&Wp[aoff1 + (size_t)ks * 2048];
        bf16x8 b0 = *(const bf16x8*)&Xt[base0 + uoff];
        bf16x8 b1 = *(const bf16x8*)&Xt[base1 + uoff];
        acc00 = __builtin_amdgcn_mfma_f32_16x16x32_bf16(a0, b0, acc00, 0, 0, 0);
        acc01 = __builtin_amdgcn_mfma_f32_16x16x32_bf16(a0, b1, acc01, 0, 0, 0);
        acc10 = __builtin_amdgcn_mfma_f32_16x16x32_bf16(a1, b0, acc10, 0, 0, 0);
        acc11 = __builtin_amdgcn_mfma_f32_16x16x32_bf16(a1, b1, acc11, 0, 0, 0);
    }

    const int ocb = ot * 64 + wr * 32;
    const int scol = s0 + wc * 32 + ln;
    float* ob = out + (size_t)b * 262144;
    #pragma unroll
    for (int r = 0; r < 4; ++r) {
        int oc0 = ocb + kc * 4 + r;
        float b0v = bias[oc0];
        ob[(size_t)oc0 * 1024 + scol]      = acc00[r] + b0v;
        ob[(size_t)oc0 * 1024 + scol + 16] = acc01[r] + b0v;
        int oc1 = ocb + 16 + kc * 4 + r;
        float b1v = bias[oc1];
        ob[(size_t)oc1 * 1024 + scol]      = acc10[r] + b1v;
        ob[(size_t)oc1 * 1024 + scol + 16] = acc11[r] + b1v;
    }
}

// ---- kqv 1x1 conv as bf16 MFMA GEMM (LDS-free), writes f32 channel-major ----
__global__ __launch_bounds__(256) void mfma_kqv_kernel(
    const unsigned short* __restrict__ Wq, const unsigned short* __restrict__ Xt,
    const float* __restrict__ bias, float* __restrict__ kqv)
{
    const int b  = blockIdx.z;
    const int ot = blockIdx.y;                     // 0..5
    const int s0 = blockIdx.x * 64;
    const int tid = threadIdx.x;
    const int lane = tid & 63, w = tid >> 6;
    const int wr = w >> 1, wc = w & 1;
    const int kc = lane >> 4, ln = lane & 15;

    const size_t aoff0 = ((size_t)(ot * 32 + wr * 2 + 0) * 64 + lane) * 8;
    const size_t aoff1 = ((size_t)(ot * 32 + wr * 2 + 1) * 64 + lane) * 8;

    int s_a = s0 + wc * 32 + ln;
    int base0 = ((b * 1156 + ((s_a >> 5) + 1) * 34 + ((s_a & 31) + 1)) * 256 + kc * 8);
    int s_b2 = s_a + 16;
    int base1 = ((b * 1156 + ((s_b2 >> 5) + 1) * 34 + ((s_b2 & 31) + 1)) * 256 + kc * 8);

    f32x4 acc00 = {}, acc01 = {}, acc10 = {}, acc11 = {};

    #pragma unroll 2
    for (int ks = 0; ks < 8; ++ks) {
        bf16x8 a0 = *(const bf16x8*)&Wq[aoff0 + (size_t)ks * 2048];
        bf16x8 a1 = *(const bf16x8*)&Wq[aoff1 + (size_t)ks * 2048];
        bf16x8 b0 = *(const bf16x8*)&Xt[base0 + ks * 32];
        bf16x8 b1 = *(const bf16x8*)&Xt[base1 + ks * 32];
        acc00 = __builtin_amdgcn_mfma_f32_16x16x32_bf16(a0, b0, acc00, 0, 0, 0);
        acc01 = __builtin_amdgcn_mfma_f32_16x16x32_bf16(a0, b1, acc01, 0, 0, 0);
        acc10 = __builtin_amdgcn_mfma_f32_16x16x32_bf16(a1, b0, acc10, 0, 0, 0);
        acc11 = __builtin_amdgcn_mfma_f32_16x16x32_bf16(a1, b1, acc11, 0, 0, 0);
    }

    const int ocb = ot * 64 + wr * 32;
    const int scol = s0 + wc * 32 + ln;
    float* ob = kqv + (size_t)b * 393216;
    #pragma unroll
    for (int r = 0; r < 4; ++r) {
        int oc0 = ocb + kc * 4 + r;
        float b0v = bias[oc0] * ((oc0 >= 160 && oc0 < 320) ? QSCALE : 1.0f);
        ob[(size_t)oc0 * 1024 + scol]      = acc00[r] + b0v;
        ob[(size_t)oc0 * 1024 + scol + 16] = acc01[r] + b0v;
        int oc1 = ocb + 16 + kc * 4 + r;
        float b1v = bias[oc1] * ((oc1 >= 160 && oc1 < 320) ? QSCALE : 1.0f);
        ob[(size_t)oc1 * 1024 + scol]      = acc10[r] + b1v;
        ob[(size_t)oc1 * 1024 + scol + 16] = acc11[r] + b1v;
    }
}

// ---------------- head-sum of q: qsum[b][s][d] = sum_n q[b][n*20480 + s*20 + d] ----
__global__ void qsum_kernel(const float* __restrict__ kqv, float* __restrict__ qsum)
{
    int idx = blockIdx.x * 256 + threadIdx.x;   // 8 * 20480 = 163840
    int b = idx / 20480, t = idx - b * 20480;
    const float* qb = kqv + (size_t)b * 393216 + 163840 + t;
    float s = 0.0f;
    #pragma unroll
    for (int n = 0; n < 8; ++n) s += qb[(size_t)n * 20480];
    qsum[idx] = s;
}

// ---------------- rel logits (relative coords): R*_rel[b][.][m] -------------------
__global__ void rel_kernel(const float* __restrict__ qsum,
    const float* __restrict__ rel_h, const float* __restrict__ rel_w,
    float* __restrict__ Rh, float* __restrict__ Rw)
{
    int idx = blockIdx.x * 256 + threadIdx.x;   // 8 * 1024 * 63 = 516096
    int b = idx / 64512, rem = idx - b * 64512;
    int s = rem / 63, mm = rem - s * 63;
    int y = s >> 5, x = s & 31;
    const float* qrow = qsum + (size_t)b * 20480 + s * 20;
    const float* rh = rel_h + mm * 20;
    const float* rw = rel_w + mm * 20;
    float sh = 0.0f, sw = 0.0f;
    #pragma unroll
    for (int d = 0; d < 20; ++d) {
        float qv = qrow[d];
        sh += qv * rh[d];
        sw += qv * rw[d];
    }
    Rw[(size_t)b * 64512 + s * 63 + mm] = sw;                 // [b][y*32+x][m]
    Rh[(size_t)b * 64512 + (x * 32 + y) * 63 + mm] = sh;      // [b][x*32+y][m]
}

// ---------------- split-KV attention partials -------------------------------------
__global__ __launch_bounds__(256, 4) void attn_part_kernel(
    const float* __restrict__ kqv, const float* __restrict__ Rh,
    const float* __restrict__ Rw, float* __restrict__ part)
{
    const int bn = blockIdx.y;            // 0..63
    const int b = bn >> 3, n = bn & 7;
    const int chunk = blockIdx.z;         // 0..NCHUNK-1
    const int i = blockIdx.x * 256 + threadIdx.x;   // query row 0..1023
    const int y1 = i >> 5, x1 = i & 31;

    const float* base = kqv + (size_t)b * 393216;
    const float* qrow = base + 163840 + n * 20480 + i * 20;
    float q[20];
    #pragma unroll
    for (int d0 = 0; d0 < 20; d0 += 4) {
        float4 t = *(const float4*)&qrow[d0];
        q[d0] = t.x; q[d0 + 1] = t.y; q[d0 + 2] = t.z; q[d0 + 3] = t.w;
    }

    float Rwreg[32];
    const float* rwrow = Rw + (size_t)b * 64512 + i * 63;
    #pragma unroll
    for (int x2 = 0; x2 < 32; ++x2) Rwreg[x2] = rwrow[31 + x2 - x1];
    const float* rhrow = Rh + (size_t)b * 64512 + (x1 * 32 + y1) * 63;
    const int y2base = chunk * (CHUNK / 32);

    const float* Kb = base + n * 20480 + chunk * CHUNK * 20;
    const float* Vb = base + 327680 + n * 8192 + chunk * CHUNK * 8;

    float m = -1e30f, lsum = 0.0f;
    float acc[8] = {};

    for (int t = 0; t < CHUNK / 32; ++t) {
        float rh = rhrow[31 + y2base + t - y1];
        const float* krow = Kb + t * 32 * 20;
        const float* vrow = Vb + t * 32 * 8;
        #pragma unroll
        for (int x2 = 0; x2 < 32; ++x2) {
            float4 k0 = *(const float4*)&krow[x2 * 20 + 0];
            float4 k1 = *(const float4*)&krow[x2 * 20 + 4];
            float4 k2 = *(const float4*)&krow[x2 * 20 + 8];
            float4 k3 = *(const float4*)&krow[x2 * 20 + 12];
            float4 k4 = *(const float4*)&krow[x2 * 20 + 16];
            float d0 = q[0]  * k0.x + q[1]  * k0.y + q[2]  * k0.z + q[3]  * k0.w;
            float d1 = q[4]  * k1.x + q[5]  * k1.y + q[6]  * k1.z + q[7]  * k1.w;
            float d2 = q[8]  * k2.x + q[9]  * k2.y + q[10] * k2.z + q[11] * k2.w;
            float d3 = q[12] * k3.x + q[13] * k3.y + q[14] * k3.z + q[15] * k3.w;
            float d4 = q[16] * k4.x + q[17] * k4.y + q[18] * k4.z + q[19] * k4.w;
            float logit = ((d0 + d1) + (d2 + d3)) + d4 + rh + Rwreg[x2];

            if (logit > m) {
                float sc = __expf(m - logit);
                lsum *= sc;
                #pragma unroll
                for (int e = 0; e < 8; ++e) acc[e] *= sc;
                m = logit;
            }
            float p = __expf(logit - m);
            lsum += p;
            float4 v0 = *(const float4*)&vrow[x2 * 8];
            float4 v1 = *(const float4*)&vrow[x2 * 8 + 4];
            acc[0] += p * v0.x; acc[1] += p * v0.y; acc[2] += p * v0.z; acc[3] += p * v0.w;
            acc[4] += p * v1.x; acc[5] += p * v1.y; acc[6] += p * v1.z; acc[7] += p * v1.w;
        }
    }

    const int ridx = bn * 1024 + i;
    float* pp = part + (size_t)chunk * 10 * 65536 + ridx;
    pp[0]     = m;
    pp[65536] = lsum;
    #pragma unroll
    for (int e = 0; e < 8; ++e) pp[(size_t)(2 + e) * 65536] = acc[e];
}

// ---------------- combine split-KV partials ---------------------------------------
__global__ __launch_bounds__(256) void attn_combine_kernel(
    const float* __restrict__ part, float* __restrict__ attnout)
{
    const int idx = blockIdx.x * 256 + threadIdx.x;
    float mc[NCHUNK];
    float M = -1e30f;
    #pragma unroll
    for (int c = 0; c < NCHUNK; ++c) {
        mc[c] = part[(size_t)(c * 10) * 65536 + idx];
        M = fmaxf(M, mc[c]);
    }
    float l = 0.0f, acc[8] = {};
    #pragma unroll
    for (int c = 0; c < NCHUNK; ++c) {
        float w = __expf(mc[c] - M);
        const float* pp = part + (size_t)(c * 10) * 65536 + idx;
        l += w * pp[65536];
        #pragma unroll
        for (int e = 0; e < 8; ++e) acc[e] += w * pp[(size_t)(2 + e) * 65536];
    }
    float inv = 1.0f / l;
    float4 o0 = {acc[0] * inv, acc[1] * inv, acc[2] * inv, acc[3] * inv};
    float4 o1 = {acc[4] * inv, acc[5] * inv, acc[6] * inv, acc[7] * inv};
    float* outp = attnout + (size_t)idx * 8;
    *(float4*)&outp[0] = o0;
    *(float4*)&outp[4] = o1;
}

// ---------------- attn 1x1 conv (64->64) into output channels 192..255 ------------
__global__ __launch_bounds__(256) void attn_out_conv_kernel(
    const float* __restrict__ attn, const float* __restrict__ W,
    const float* __restrict__ bias, float* __restrict__ out)
{
    const int b  = blockIdx.z;
    const int oc = blockIdx.y;
    const int s  = blockIdx.x * 256 + threadIdx.x;
    const float* ab = attn + (size_t)b * 65536;
    float sum = bias[oc];
    #pragma unroll
    for (int c = 0; c < 64; ++c)
        sum += W[oc * 64 + c] * ab[(size_t)c * 1024 + s];
    out[(size_t)b * 262144 + (size_t)(192 + oc) * 1024 + s] = sum;
}

extern "C" void kernel_launch(void* const* d_in, const int* in_sizes, int n_in,
                              void* d_out, int out_size, void* d_ws, size_t ws_size,
                              hipStream_t stream)
{
    const float* x          = (const float*)d_in[0];
    const float* kqv_w      = (const float*)d_in[1];
    const float* kqv_b      = (const float*)d_in[2];
    const float* conv_out_w = (const float*)d_in[3];
    const float* conv_out_b = (const float*)d_in[4];
    const float* attn_w     = (const float*)d_in[5];
    const float* attn_b     = (const float*)d_in[6];
    const float* rel_h      = (const float*)d_in[7];
    const float* rel_w      = (const float*)d_in[8];
    float* out = (float*)d_out;
    float* ws  = (float*)d_ws;

    float* ws_kqv  = ws;                   // 3,145,728 f32
    float* ws_qsum = ws + 3145728;         //   163,840
    float* ws_rw   = ws + 3309568;         //   516,096
    float* ws_rh   = ws + 3825664;         //   516,096
    float* ws_attn = ws + 4341760;         //   524,288
    float* ws_part = ws + 4866048;         // 2,621,440  (total 7,487,488 f32 = ~30 MB)

    // Aliases for transient packed tensors (dead before their hosts are written):
    unsigned short* Xt = (unsigned short*)ws_part;            // 4.73 MB, dead before attn_part writes
    unsigned short* Wp = (unsigned short*)ws_attn;            // 884,736 B
    unsigned short* Wq = (unsigned short*)(ws_attn + 221184); // 196,608 B; both dead before attn_combine

    pack_xt_kernel   <<<1156, 256, 0, stream>>>(x, Xt);
    pack_wconv_kernel<<< 216, 256, 0, stream>>>(conv_out_w, Wp);
    pack_wkqv_kernel <<<  48, 256, 0, stream>>>(kqv_w, Wq);
    mfma_kqv_kernel    <<<dim3(16, 6, 8), 256, 0, stream>>>(Wq, Xt, kqv_b, ws_kqv);
    mfma_conv3x3_kernel<<<dim3(16, 3, 8), 256, 0, stream>>>(Wp, Xt, conv_out_b, out);
    qsum_kernel<<<640, 256, 0, stream>>>(ws_kqv, ws_qsum);
    rel_kernel <<<2016, 256, 0, stream>>>(ws_qsum, rel_h, rel_w, ws_rh, ws_rw);
    attn_part_kernel<<<dim3(4, 64, NCHUNK), 256, 0, stream>>>(ws_kqv, ws_rh, ws_rw, ws_part);
    attn_combine_kernel<<<256, 256, 0, stream>>>(ws_part, ws_attn);
    attn_out_conv_kernel<<<dim3(4, 64, 8), 256, 0, stream>>>(ws_attn, attn_w, attn_b, out);
}

// Round 4
// 172.218 us; speedup vs baseline: 3.9060x; 1.3209x over previous
//
#include <hip/hip_runtime.h>

// Problem constants: B=8, C=256, H=W=32, NH=8, DK=160, DV=64, DKH=20, DVH=8
constexpr float QSCALE = 0.22360679774997896f; // 1/sqrt(20)
constexpr float LOG2E  = 1.4426950408889634f;

typedef __attribute__((ext_vector_type(8))) short bf16x8;
typedef __attribute__((ext_vector_type(4))) float f32x4;

__device__ __forceinline__ unsigned short f2bf(float f) {
    unsigned u = __float_as_uint(f);
    u = (u + 0x7FFFu + ((u >> 16) & 1u)) >> 16;   // RNE
    return (unsigned short)u;
}

// ---- pack x (f32 NCHW) -> Xt bf16 [b][(y+1)*34+(x+1)][256ch], zero-padded halo ----
__global__ __launch_bounds__(256) void pack_xt_kernel(
    const float* __restrict__ X, unsigned short* __restrict__ Xt)
{
    int t = blockIdx.x * 256 + threadIdx.x;        // 8*1156*32 = 295936
    int b = t / 36992, rem = t - b * 36992;
    int spad = rem >> 5, cc = rem & 31;
    int yp = spad / 34, xp = spad - yp * 34;
    bf16x8 v = {};
    if (yp >= 1 && yp <= 32 && xp >= 1 && xp <= 32) {
        const float* src = X + (size_t)b * 262144 + (size_t)(cc * 8) * 1024
                             + (yp - 1) * 32 + (xp - 1);
        #pragma unroll
        for (int j = 0; j < 8; ++j) v[j] = (short)f2bf(src[(size_t)j * 1024]);
    }
    *(bf16x8*)&Xt[((size_t)b * 1156 + spad) * 256 + cc * 8] = v;
}

// ---- pack conv_out_w (OIHW f32) -> fragment-order bf16, K reordered k'=r*256+c ----
__global__ __launch_bounds__(256) void pack_wconv_kernel(
    const float* __restrict__ W, unsigned short* __restrict__ Wp)
{
    int t = blockIdx.x * 256 + threadIdx.x;        // 3*72*4*64 = 55296
    int l = t & 63;
    int rb = (t >> 6) & 3;
    int ks = (t >> 8) % 72;
    int ot = t / 18432;
    int oc = ot * 64 + rb * 16 + (l & 15);
    int kbase = ks * 32 + (l >> 4) * 8;
    bf16x8 v;
    #pragma unroll
    for (int j = 0; j < 8; ++j) {
        int kp = kbase + j;
        int r = kp >> 8, c = kp & 255;             // k' = r*256 + c
        v[j] = (short)f2bf(W[((size_t)oc * 256 + c) * 9 + r]);
    }
    *(bf16x8*)&Wp[(size_t)t * 8] = v;
}

// ---- pack kqv_w -> fragment-order bf16 (QSCALE folded into q rows) ----
__global__ __launch_bounds__(256) void pack_wkqv_kernel(
    const float* __restrict__ W, unsigned short* __restrict__ Wq)
{
    int t = blockIdx.x * 256 + threadIdx.x;        // 6*8*4*64 = 12288
    int l = t & 63;
    int rb = (t >> 6) & 3;
    int ks = (t >> 8) & 7;
    int ot = t / 2048;
    int oc = ot * 64 + rb * 16 + (l & 15);
    float sc = (oc >= 160 && oc < 320) ? QSCALE : 1.0f;
    int kbase = ks * 32 + (l >> 4) * 8;
    bf16x8 v;
    #pragma unroll
    for (int j = 0; j < 8; ++j)
        v[j] = (short)f2bf(W[(size_t)oc * 256 + kbase + j] * sc);
    *(bf16x8*)&Wq[(size_t)t * 8] = v;
}

// ---- conv_out 3x3 as bf16 MFMA implicit GEMM (LDS-free, direct fragments) ----
__global__ __launch_bounds__(256) void mfma_conv3x3_kernel(
    const unsigned short* __restrict__ Wp, const unsigned short* __restrict__ Xt,
    const float* __restrict__ bias, float* __restrict__ out)
{
    const int b  = blockIdx.z;
    const int ot = blockIdx.y;                     // 0..2
    const int s0 = blockIdx.x * 64;
    const int tid = threadIdx.x;
    const int lane = tid & 63, w = tid >> 6;
    const int wr = w >> 1, wc = w & 1;
    const int kc = lane >> 4, ln = lane & 15;

    const size_t aoff0 = ((size_t)(ot * 288 + wr * 2 + 0) * 64 + lane) * 8;
    const size_t aoff1 = ((size_t)(ot * 288 + wr * 2 + 1) * 64 + lane) * 8;

    int s_a = s0 + wc * 32 + ln;
    int base0 = ((b * 1156 + ((s_a >> 5) + 1) * 34 + ((s_a & 31) + 1)) * 256 + kc * 8);
    int s_b2 = s_a + 16;
    int base1 = ((b * 1156 + ((s_b2 >> 5) + 1) * 34 + ((s_b2 & 31) + 1)) * 256 + kc * 8);

    f32x4 acc00 = {}, acc01 = {}, acc10 = {}, acc11 = {};

    #pragma unroll 2
    for (int ks = 0; ks < 72; ++ks) {
        int r = ks >> 3;
        int ky = r / 3, kx = r - ky * 3;
        int uoff = ((ky - 1) * 34 + (kx - 1)) * 256 + (ks & 7) * 32;
        bf16x8 a0 = *(const bf16x8*)&Wp[aoff0 + (size_t)ks * 2048];
        bf16x8 a1 = *(const bf16x8*)&Wp[aoff1 + (size_t)ks * 2048];
        bf16x8 b0 = *(const bf16x8*)&Xt[base0 + uoff];
        bf16x8 b1 = *(const bf16x8*)&Xt[base1 + uoff];
        acc00 = __builtin_amdgcn_mfma_f32_16x16x32_bf16(a0, b0, acc00, 0, 0, 0);
        acc01 = __builtin_amdgcn_mfma_f32_16x16x32_bf16(a0, b1, acc01, 0, 0, 0);
        acc10 = __builtin_amdgcn_mfma_f32_16x16x32_bf16(a1, b0, acc10, 0, 0, 0);
        acc11 = __builtin_amdgcn_mfma_f32_16x16x32_bf16(a1, b1, acc11, 0, 0, 0);
    }

    const int ocb = ot * 64 + wr * 32;
    const int scol = s0 + wc * 32 + ln;
    float* ob = out + (size_t)b * 262144;
    #pragma unroll
    for (int r = 0; r < 4; ++r) {
        int oc0 = ocb + kc * 4 + r;
        float b0v = bias[oc0];
        ob[(size_t)oc0 * 1024 + scol]      = acc00[r] + b0v;
        ob[(size_t)oc0 * 1024 + scol + 16] = acc01[r] + b0v;
        int oc1 = ocb + 16 + kc * 4 + r;
        float b1v = bias[oc1];
        ob[(size_t)oc1 * 1024 + scol]      = acc10[r] + b1v;
        ob[(size_t)oc1 * 1024 + scol + 16] = acc11[r] + b1v;
    }
}

// ---- kqv 1x1 conv as bf16 MFMA GEMM (LDS-free), writes f32 channel-major ----
__global__ __launch_bounds__(256) void mfma_kqv_kernel(
    const unsigned short* __restrict__ Wq, const unsigned short* __restrict__ Xt,
    const float* __restrict__ bias, float* __restrict__ kqv)
{
    const int b  = blockIdx.z;
    const int ot = blockIdx.y;                     // 0..5
    const int s0 = blockIdx.x * 64;
    const int tid = threadIdx.x;
    const int lane = tid & 63, w = tid >> 6;
    const int wr = w >> 1, wc = w & 1;
    const int kc = lane >> 4, ln = lane & 15;

    const size_t aoff0 = ((size_t)(ot * 32 + wr * 2 + 0) * 64 + lane) * 8;
    const size_t aoff1 = ((size_t)(ot * 32 + wr * 2 + 1) * 64 + lane) * 8;

    int s_a = s0 + wc * 32 + ln;
    int base0 = ((b * 1156 + ((s_a >> 5) + 1) * 34 + ((s_a & 31) + 1)) * 256 + kc * 8);
    int s_b2 = s_a + 16;
    int base1 = ((b * 1156 + ((s_b2 >> 5) + 1) * 34 + ((s_b2 & 31) + 1)) * 256 + kc * 8);

    f32x4 acc00 = {}, acc01 = {}, acc10 = {}, acc11 = {};

    #pragma unroll 2
    for (int ks = 0; ks < 8; ++ks) {
        bf16x8 a0 = *(const bf16x8*)&Wq[aoff0 + (size_t)ks * 2048];
        bf16x8 a1 = *(const bf16x8*)&Wq[aoff1 + (size_t)ks * 2048];
        bf16x8 b0 = *(const bf16x8*)&Xt[base0 + ks * 32];
        bf16x8 b1 = *(const bf16x8*)&Xt[base1 + ks * 32];
        acc00 = __builtin_amdgcn_mfma_f32_16x16x32_bf16(a0, b0, acc00, 0, 0, 0);
        acc01 = __builtin_amdgcn_mfma_f32_16x16x32_bf16(a0, b1, acc01, 0, 0, 0);
        acc10 = __builtin_amdgcn_mfma_f32_16x16x32_bf16(a1, b0, acc10, 0, 0, 0);
        acc11 = __builtin_amdgcn_mfma_f32_16x16x32_bf16(a1, b1, acc11, 0, 0, 0);
    }

    const int ocb = ot * 64 + wr * 32;
    const int scol = s0 + wc * 32 + ln;
    float* ob = kqv + (size_t)b * 393216;
    #pragma unroll
    for (int r = 0; r < 4; ++r) {
        int oc0 = ocb + kc * 4 + r;
        float b0v = bias[oc0] * ((oc0 >= 160 && oc0 < 320) ? QSCALE : 1.0f);
        ob[(size_t)oc0 * 1024 + scol]      = acc00[r] + b0v;
        ob[(size_t)oc0 * 1024 + scol + 16] = acc01[r] + b0v;
        int oc1 = ocb + 16 + kc * 4 + r;
        float b1v = bias[oc1] * ((oc1 >= 160 && oc1 < 320) ? QSCALE : 1.0f);
        ob[(size_t)oc1 * 1024 + scol]      = acc10[r] + b1v;
        ob[(size_t)oc1 * 1024 + scol + 16] = acc11[r] + b1v;
    }
}

// ---- pack q/k (f32 kqv flat) -> bf16 [bn*1024+i][32] zero-padded; q scaled LOG2E ----
__global__ __launch_bounds__(256) void pack_qk_kernel(
    const float* __restrict__ kqv, unsigned short* __restrict__ Kb,
    unsigned short* __restrict__ Qb)
{
    int idx = blockIdx.x * 256 + threadIdx.x;      // 131072
    int type = idx >> 16;                          // 0: K, 1: Q
    int r = idx & 65535;
    int bn = r >> 10, i = r & 1023;
    int b = bn >> 3, n = bn & 7;
    const float* src = kqv + (size_t)b * 393216 + (type ? 163840 : 0) + n * 20480 + i * 20;
    float sc = type ? LOG2E : 1.0f;
    unsigned short* dst = (type ? Qb : Kb) + ((size_t)bn * 1024 + i) * 32;
    bf16x8 v[4] = {{}, {}, {}, {}};
    #pragma unroll
    for (int d = 0; d < 20; ++d) v[d >> 3][d & 7] = (short)f2bf(src[d] * sc);
    #pragma unroll
    for (int j = 0; j < 4; ++j) *(bf16x8*)&dst[j * 8] = v[j];
}

// ---------------- head-sum of q: qsum[b][s][d] = sum_n q[b][n*20480 + s*20 + d] ----
__global__ void qsum_kernel(const float* __restrict__ kqv, float* __restrict__ qsum)
{
    int idx = blockIdx.x * 256 + threadIdx.x;   // 8 * 20480 = 163840
    int b = idx / 20480, t = idx - b * 20480;
    const float* qb = kqv + (size_t)b * 393216 + 163840 + t;
    float s = 0.0f;
    #pragma unroll
    for (int n = 0; n < 8; ++n) s += qb[(size_t)n * 20480];
    qsum[idx] = s;
}

// ---------------- rel logits (relative coords), scaled by LOG2E -------------------
__global__ void rel_kernel(const float* __restrict__ qsum,
    const float* __restrict__ rel_h, const float* __restrict__ rel_w,
    float* __restrict__ Rh, float* __restrict__ Rw)
{
    int idx = blockIdx.x * 256 + threadIdx.x;   // 8 * 1024 * 63 = 516096
    int b = idx / 64512, rem = idx - b * 64512;
    int s = rem / 63, mm = rem - s * 63;
    int y = s >> 5, x = s & 31;
    const float* qrow = qsum + (size_t)b * 20480 + s * 20;
    const float* rh = rel_h + mm * 20;
    const float* rw = rel_w + mm * 20;
    float sh = 0.0f, sw = 0.0f;
    #pragma unroll
    for (int d = 0; d < 20; ++d) {
        float qv = qrow[d];
        sh += qv * rh[d];
        sw += qv * rw[d];
    }
    Rw[(size_t)b * 64512 + s * 63 + mm] = sw * LOG2E;            // [b][y*32+x][m]
    Rh[(size_t)b * 64512 + (x * 32 + y) * 63 + mm] = sh * LOG2E; // [b][x*32+y][m]
}

// ---------------- MFMA flash attention: block = (b,n) x 64 queries ---------------
// S^T = mfma(K_frag, Q_frag): lane holds 16 logits (4 accs x 4 regs) for query
// col = lane&15; key = kv0 + f*16 + (lane>>4)*4 + r. Final combine over lane>>4.
__global__ __launch_bounds__(256, 4) void attn_mfma_kernel(
    const unsigned short* __restrict__ Qb, const unsigned short* __restrict__ Kb,
    const float* __restrict__ kqv, const float* __restrict__ Rh,
    const float* __restrict__ Rw, float* __restrict__ attnout)
{
    const int bn = blockIdx.y;                    // b*8+n
    const int b = bn >> 3, n = bn & 7;
    const int i0 = blockIdx.x * 64;
    const int tid = threadIdx.x;
    const int lane = tid & 63, w = tid >> 6;

    __shared__ float RhS[64][33];
    __shared__ float RwS[64][33];
    {
        int q = tid & 63, seg = tid >> 6;
        int i = i0 + q, y1 = i >> 5, x1 = i & 31;
        const float* rh = Rh + (size_t)b * 64512 + (x1 * 32 + y1) * 63 + 31 - y1 + seg * 8;
        const float* rw = Rw + (size_t)b * 64512 + i * 63 + 31 - x1 + seg * 8;
        #pragma unroll
        for (int j = 0; j < 8; ++j) {
            RhS[q][seg * 8 + j] = rh[j];
            RwS[q][seg * 8 + j] = rw[j];
        }
    }
    __syncthreads();

    const int ql = lane & 15, g = lane >> 4;
    const int qw = i0 + w * 16;

    bf16x8 qf = *(const bf16x8*)&Qb[((size_t)bn * 1024 + qw + ql) * 32 + g * 8];
    const unsigned short* kp = Kb + ((size_t)bn * 1024 + ql) * 32 + g * 8;
    const float* vp = kqv + (size_t)b * 393216 + 327680 + n * 8192 + (4 * g) * 8;

    const float* rhrow = &RhS[w * 16 + ql][0];
    float rwA[4], rwB[4];
    #pragma unroll
    for (int r = 0; r < 4; ++r) {
        rwA[r] = RwS[w * 16 + ql][4 * g + r];
        rwB[r] = RwS[w * 16 + ql][16 + 4 * g + r];
    }

    float m = -1e30f, lsum = 0.0f;
    float oacc[8] = {};

    #pragma unroll 1
    for (int kt = 0; kt < 16; ++kt) {
        bf16x8 k0 = *(const bf16x8*)&kp[0 * 512];
        bf16x8 k1 = *(const bf16x8*)&kp[1 * 512];
        bf16x8 k2 = *(const bf16x8*)&kp[2 * 512];
        bf16x8 k3 = *(const bf16x8*)&kp[3 * 512];
        f32x4 s0 = {}, s1 = {}, s2 = {}, s3 = {};
        s0 = __builtin_amdgcn_mfma_f32_16x16x32_bf16(k0, qf, s0, 0, 0, 0);
        s1 = __builtin_amdgcn_mfma_f32_16x16x32_bf16(k1, qf, s1, 0, 0, 0);
        s2 = __builtin_amdgcn_mfma_f32_16x16x32_bf16(k2, qf, s2, 0, 0, 0);
        s3 = __builtin_amdgcn_mfma_f32_16x16x32_bf16(k3, qf, s3, 0, 0, 0);

        float rh0 = rhrow[2 * kt];
        float rh1 = rhrow[2 * kt + 1];
        float lg[16];
        #pragma unroll
        for (int r = 0; r < 4; ++r) {
            lg[0 + r]  = s0[r] + rh0 + rwA[r];
            lg[4 + r]  = s1[r] + rh0 + rwB[r];
            lg[8 + r]  = s2[r] + rh1 + rwA[r];
            lg[12 + r] = s3[r] + rh1 + rwB[r];
        }
        float t0 = fmaxf(fmaxf(lg[0], lg[1]), fmaxf(lg[2], lg[3]));
        float t1 = fmaxf(fmaxf(lg[4], lg[5]), fmaxf(lg[6], lg[7]));
        float t2 = fmaxf(fmaxf(lg[8], lg[9]), fmaxf(lg[10], lg[11]));
        float t3 = fmaxf(fmaxf(lg[12], lg[13]), fmaxf(lg[14], lg[15]));
        float tmax = fmaxf(fmaxf(t0, t1), fmaxf(t2, t3));
        float mn = fmaxf(m, tmax);
        float sc = exp2f(m - mn);
        m = mn;
        lsum *= sc;
        #pragma unroll
        for (int e = 0; e < 8; ++e) oacc[e] *= sc;

        const float* vt = vp + kt * 512;          // kv0*8
        #pragma unroll
        for (int f = 0; f < 4; ++f) {
            #pragma unroll
            for (int r = 0; r < 4; ++r) {
                float p = exp2f(lg[f * 4 + r] - mn);
                lsum += p;
                const float* vr = vt + (f * 16 + r) * 8;
                float4 v0 = *(const float4*)vr;
                float4 v1 = *(const float4*)(vr + 4);
                oacc[0] += p * v0.x; oacc[1] += p * v0.y;
                oacc[2] += p * v0.z; oacc[3] += p * v0.w;
                oacc[4] += p * v1.x; oacc[5] += p * v1.y;
                oacc[6] += p * v1.z; oacc[7] += p * v1.w;
            }
        }
        kp += 2048;                                // 64 keys * 32 elems
    }

    // combine the 4 key-residue partials (lane>>4 groups) per query
    #pragma unroll
    for (int mask = 16; mask <= 32; mask <<= 1) {
        float mo = __shfl_xor(m, mask, 64);
        float lo = __shfl_xor(lsum, mask, 64);
        float mn = fmaxf(m, mo);
        float sa = exp2f(m - mn), sb = exp2f(mo - mn);
        lsum = lsum * sa + lo * sb;
        #pragma unroll
        for (int e = 0; e < 8; ++e) {
            float ao = __shfl_xor(oacc[e], mask, 64);
            oacc[e] = oacc[e] * sa + ao * sb;
        }
        m = mn;
    }
    if (lane < 16) {
        float inv = 1.0f / lsum;
        float* op = attnout + ((size_t)bn * 1024 + qw + ql) * 8;
        float4 o0 = {oacc[0] * inv, oacc[1] * inv, oacc[2] * inv, oacc[3] * inv};
        float4 o1 = {oacc[4] * inv, oacc[5] * inv, oacc[6] * inv, oacc[7] * inv};
        *(float4*)op = o0;
        *(float4*)(op + 4) = o1;
    }
}

// ---------------- attn 1x1 conv (64->64) into output channels 192..255 ------------
__global__ __launch_bounds__(256) void attn_out_conv_kernel(
    const float* __restrict__ attn, const float* __restrict__ W,
    const float* __restrict__ bias, float* __restrict__ out)
{
    const int b  = blockIdx.z;
    const int oc = blockIdx.y;
    const int s  = blockIdx.x * 256 + threadIdx.x;
    const float* ab = attn + (size_t)b * 65536;
    float sum = bias[oc];
    #pragma unroll
    for (int c = 0; c < 64; ++c)
        sum += W[oc * 64 + c] * ab[(size_t)c * 1024 + s];
    out[(size_t)b * 262144 + (size_t)(192 + oc) * 1024 + s] = sum;
}

extern "C" void kernel_launch(void* const* d_in, const int* in_sizes, int n_in,
                              void* d_out, int out_size, void* d_ws, size_t ws_size,
                              hipStream_t stream)
{
    const float* x          = (const float*)d_in[0];
    const float* kqv_w      = (const float*)d_in[1];
    const float* kqv_b      = (const float*)d_in[2];
    const float* conv_out_w = (const float*)d_in[3];
    const float* conv_out_b = (const float*)d_in[4];
    const float* attn_w     = (const float*)d_in[5];
    const float* attn_b     = (const float*)d_in[6];
    const float* rel_h      = (const float*)d_in[7];
    const float* rel_w      = (const float*)d_in[8];
    float* out = (float*)d_out;
    float* ws  = (float*)d_ws;

    float* ws_kqv  = ws;                   // 3,145,728 f32
    float* ws_qsum = ws + 3145728;         //   163,840
    float* ws_rw   = ws + 3309568;         //   516,096
    float* ws_rh   = ws + 3825664;         //   516,096
    float* ws_attn = ws + 4341760;         //   524,288
    unsigned short* Qb = (unsigned short*)(ws + 4866048);  // 2,097,152 u16 (4 MB)
    unsigned short* Kb = (unsigned short*)(ws + 5914624);  // 2,097,152 u16 (4 MB)
    // total: 6,963,200 f32 = 27.9 MB

    // Transient aliases (dead before their hosts are written):
    unsigned short* Xt = (unsigned short*)(ws + 4866048);     // 4.73 MB over Qb/Kb; dead before pack_qk
    unsigned short* Wp = (unsigned short*)ws_attn;            // 884,736 B
    unsigned short* Wq = (unsigned short*)(ws_attn + 221184); // 196,608 B; dead before attn writes

    pack_xt_kernel   <<<1156, 256, 0, stream>>>(x, Xt);
    pack_wconv_kernel<<< 216, 256, 0, stream>>>(conv_out_w, Wp);
    pack_wkqv_kernel <<<  48, 256, 0, stream>>>(kqv_w, Wq);
    mfma_kqv_kernel    <<<dim3(16, 6, 8), 256, 0, stream>>>(Wq, Xt, kqv_b, ws_kqv);
    mfma_conv3x3_kernel<<<dim3(16, 3, 8), 256, 0, stream>>>(Wp, Xt, conv_out_b, out);
    pack_qk_kernel<<<512, 256, 0, stream>>>(ws_kqv, Kb, Qb);   // after Xt consumers
    qsum_kernel<<<640, 256, 0, stream>>>(ws_kqv, ws_qsum);
    rel_kernel <<<2016, 256, 0, stream>>>(ws_qsum, rel_h, rel_w, ws_rh, ws_rw);
    attn_mfma_kernel<<<dim3(16, 64), 256, 0, stream>>>(Qb, Kb, ws_kqv, ws_rh, ws_rw, ws_attn);
    attn_out_conv_kernel<<<dim3(4, 64, 8), 256, 0, stream>>>(ws_attn, attn_w, attn_b, out);
}

// Round 5
// 134.436 us; speedup vs baseline: 5.0038x; 1.2810x over previous
//
#include <hip/hip_runtime.h>

// Problem constants: B=8, C=256, H=W=32, NH=8, DK=160, DV=64, DKH=20, DVH=8
constexpr float QSCALE = 0.22360679774997896f; // 1/sqrt(20)
constexpr float LOG2E  = 1.4426950408889634f;

typedef __attribute__((ext_vector_type(8))) short bf16x8;
typedef __attribute__((ext_vector_type(4))) float f32x4;

__device__ __forceinline__ unsigned short f2bf(float f) {
    unsigned u = __float_as_uint(f);
    u = (u + 0x7FFFu + ((u >> 16) & 1u)) >> 16;   // RNE
    return (unsigned short)u;
}

__device__ __forceinline__ unsigned cvt_pk_bf16(float lo, float hi) {
    unsigned r;
    asm("v_cvt_pk_bf16_f32 %0, %1, %2" : "=v"(r) : "v"(lo), "v"(hi));
    return r;
}

// ---- pack x (f32 NCHW) -> Xt bf16 [b][(y+1)*34+(x+1)][256ch], zero-padded halo ----
__global__ __launch_bounds__(256) void pack_xt_kernel(
    const float* __restrict__ X, unsigned short* __restrict__ Xt)
{
    int t = blockIdx.x * 256 + threadIdx.x;        // 8*1156*32 = 295936
    int b = t / 36992, rem = t - b * 36992;
    int spad = rem >> 5, cc = rem & 31;
    int yp = spad / 34, xp = spad - yp * 34;
    bf16x8 v = {};
    if (yp >= 1 && yp <= 32 && xp >= 1 && xp <= 32) {
        const float* src = X + (size_t)b * 262144 + (size_t)(cc * 8) * 1024
                             + (yp - 1) * 32 + (xp - 1);
        #pragma unroll
        for (int j = 0; j < 8; ++j) v[j] = (short)f2bf(src[(size_t)j * 1024]);
    }
    *(bf16x8*)&Xt[((size_t)b * 1156 + spad) * 256 + cc * 8] = v;
}

// ---- pack conv_out_w (OIHW f32) -> fragment-order bf16, K reordered k'=r*256+c ----
__global__ __launch_bounds__(256) void pack_wconv_kernel(
    const float* __restrict__ W, unsigned short* __restrict__ Wp)
{
    int t = blockIdx.x * 256 + threadIdx.x;        // 3*72*4*64 = 55296
    int l = t & 63;
    int rb = (t >> 6) & 3;
    int ks = (t >> 8) % 72;
    int ot = t / 18432;
    int oc = ot * 64 + rb * 16 + (l & 15);
    int kbase = ks * 32 + (l >> 4) * 8;
    bf16x8 v;
    #pragma unroll
    for (int j = 0; j < 8; ++j) {
        int kp = kbase + j;
        int r = kp >> 8, c = kp & 255;             // k' = r*256 + c
        v[j] = (short)f2bf(W[((size_t)oc * 256 + c) * 9 + r]);
    }
    *(bf16x8*)&Wp[(size_t)t * 8] = v;
}

// ---- pack kqv_w -> fragment-order bf16 (QSCALE folded into q rows) ----
__global__ __launch_bounds__(256) void pack_wkqv_kernel(
    const float* __restrict__ W, unsigned short* __restrict__ Wq)
{
    int t = blockIdx.x * 256 + threadIdx.x;        // 6*8*4*64 = 12288
    int l = t & 63;
    int rb = (t >> 6) & 3;
    int ks = (t >> 8) & 7;
    int ot = t / 2048;
    int oc = ot * 64 + rb * 16 + (l & 15);
    float sc = (oc >= 160 && oc < 320) ? QSCALE : 1.0f;
    int kbase = ks * 32 + (l >> 4) * 8;
    bf16x8 v;
    #pragma unroll
    for (int j = 0; j < 8; ++j)
        v[j] = (short)f2bf(W[(size_t)oc * 256 + kbase + j] * sc);
    *(bf16x8*)&Wq[(size_t)t * 8] = v;
}

// ---- conv_out 3x3 as bf16 MFMA implicit GEMM (LDS-free, direct fragments) ----
__global__ __launch_bounds__(256) void mfma_conv3x3_kernel(
    const unsigned short* __restrict__ Wp, const unsigned short* __restrict__ Xt,
    const float* __restrict__ bias, float* __restrict__ out)
{
    const int b  = blockIdx.z;
    const int ot = blockIdx.y;                     // 0..2
    const int s0 = blockIdx.x * 64;
    const int tid = threadIdx.x;
    const int lane = tid & 63, w = tid >> 6;
    const int wr = w >> 1, wc = w & 1;
    const int kc = lane >> 4, ln = lane & 15;

    const size_t aoff0 = ((size_t)(ot * 288 + wr * 2 + 0) * 64 + lane) * 8;
    const size_t aoff1 = ((size_t)(ot * 288 + wr * 2 + 1) * 64 + lane) * 8;

    int s_a = s0 + wc * 32 + ln;
    int base0 = ((b * 1156 + ((s_a >> 5) + 1) * 34 + ((s_a & 31) + 1)) * 256 + kc * 8);
    int s_b2 = s_a + 16;
    int base1 = ((b * 1156 + ((s_b2 >> 5) + 1) * 34 + ((s_b2 & 31) + 1)) * 256 + kc * 8);

    f32x4 acc00 = {}, acc01 = {}, acc10 = {}, acc11 = {};

    #pragma unroll 2
    for (int ks = 0; ks < 72; ++ks) {
        int r = ks >> 3;
        int ky = r / 3, kx = r - ky * 3;
        int uoff = ((ky - 1) * 34 + (kx - 1)) * 256 + (ks & 7) * 32;
        bf16x8 a0 = *(const bf16x8*)&Wp[aoff0 + (size_t)ks * 2048];
        bf16x8 a1 = *(const bf16x8*)&Wp[aoff1 + (size_t)ks * 2048];
        bf16x8 b0 = *(const bf16x8*)&Xt[base0 + uoff];
        bf16x8 b1 = *(const bf16x8*)&Xt[base1 + uoff];
        acc00 = __builtin_amdgcn_mfma_f32_16x16x32_bf16(a0, b0, acc00, 0, 0, 0);
        acc01 = __builtin_amdgcn_mfma_f32_16x16x32_bf16(a0, b1, acc01, 0, 0, 0);
        acc10 = __builtin_amdgcn_mfma_f32_16x16x32_bf16(a1, b0, acc10, 0, 0, 0);
        acc11 = __builtin_amdgcn_mfma_f32_16x16x32_bf16(a1, b1, acc11, 0, 0, 0);
    }

    const int ocb = ot * 64 + wr * 32;
    const int scol = s0 + wc * 32 + ln;
    float* ob = out + (size_t)b * 262144;
    #pragma unroll
    for (int r = 0; r < 4; ++r) {
        int oc0 = ocb + kc * 4 + r;
        float b0v = bias[oc0];
        ob[(size_t)oc0 * 1024 + scol]      = acc00[r] + b0v;
        ob[(size_t)oc0 * 1024 + scol + 16] = acc01[r] + b0v;
        int oc1 = ocb + 16 + kc * 4 + r;
        float b1v = bias[oc1];
        ob[(size_t)oc1 * 1024 + scol]      = acc10[r] + b1v;
        ob[(size_t)oc1 * 1024 + scol + 16] = acc11[r] + b1v;
    }
}

// ---- kqv 1x1 conv as bf16 MFMA GEMM (LDS-free), writes f32 channel-major ----
__global__ __launch_bounds__(256) void mfma_kqv_kernel(
    const unsigned short* __restrict__ Wq, const unsigned short* __restrict__ Xt,
    const float* __restrict__ bias, float* __restrict__ kqv)
{
    const int b  = blockIdx.z;
    const int ot = blockIdx.y;                     // 0..5
    const int s0 = blockIdx.x * 64;
    const int tid = threadIdx.x;
    const int lane = tid & 63, w = tid >> 6;
    const int wr = w >> 1, wc = w & 1;
    const int kc = lane >> 4, ln = lane & 15;

    const size_t aoff0 = ((size_t)(ot * 32 + wr * 2 + 0) * 64 + lane) * 8;
    const size_t aoff1 = ((size_t)(ot * 32 + wr * 2 + 1) * 64 + lane) * 8;

    int s_a = s0 + wc * 32 + ln;
    int base0 = ((b * 1156 + ((s_a >> 5) + 1) * 34 + ((s_a & 31) + 1)) * 256 + kc * 8);
    int s_b2 = s_a + 16;
    int base1 = ((b * 1156 + ((s_b2 >> 5) + 1) * 34 + ((s_b2 & 31) + 1)) * 256 + kc * 8);

    f32x4 acc00 = {}, acc01 = {}, acc10 = {}, acc11 = {};

    #pragma unroll 2
    for (int ks = 0; ks < 8; ++ks) {
        bf16x8 a0 = *(const bf16x8*)&Wq[aoff0 + (size_t)ks * 2048];
        bf16x8 a1 = *(const bf16x8*)&Wq[aoff1 + (size_t)ks * 2048];
        bf16x8 b0 = *(const bf16x8*)&Xt[base0 + ks * 32];
        bf16x8 b1 = *(const bf16x8*)&Xt[base1 + ks * 32];
        acc00 = __builtin_amdgcn_mfma_f32_16x16x32_bf16(a0, b0, acc00, 0, 0, 0);
        acc01 = __builtin_amdgcn_mfma_f32_16x16x32_bf16(a0, b1, acc01, 0, 0, 0);
        acc10 = __builtin_amdgcn_mfma_f32_16x16x32_bf16(a1, b0, acc10, 0, 0, 0);
        acc11 = __builtin_amdgcn_mfma_f32_16x16x32_bf16(a1, b1, acc11, 0, 0, 0);
    }

    const int ocb = ot * 64 + wr * 32;
    const int scol = s0 + wc * 32 + ln;
    float* ob = kqv + (size_t)b * 393216;
    #pragma unroll
    for (int r = 0; r < 4; ++r) {
        int oc0 = ocb + kc * 4 + r;
        float b0v = bias[oc0] * ((oc0 >= 160 && oc0 < 320) ? QSCALE : 1.0f);
        ob[(size_t)oc0 * 1024 + scol]      = acc00[r] + b0v;
        ob[(size_t)oc0 * 1024 + scol + 16] = acc01[r] + b0v;
        int oc1 = ocb + 16 + kc * 4 + r;
        float b1v = bias[oc1] * ((oc1 >= 160 && oc1 < 320) ? QSCALE : 1.0f);
        ob[(size_t)oc1 * 1024 + scol]      = acc10[r] + b1v;
        ob[(size_t)oc1 * 1024 + scol + 16] = acc11[r] + b1v;
    }
}

// ---- pack q/k (f32 kqv flat) -> bf16 [bn*1024+i][32] zero-padded; q scaled LOG2E ----
__global__ __launch_bounds__(256) void pack_qk_kernel(
    const float* __restrict__ kqv, unsigned short* __restrict__ Kb,
    unsigned short* __restrict__ Qb)
{
    int idx = blockIdx.x * 256 + threadIdx.x;      // 131072
    int type = idx >> 16;                          // 0: K, 1: Q
    int r = idx & 65535;
    int bn = r >> 10, i = r & 1023;
    int b = bn >> 3, n = bn & 7;
    const float* src = kqv + (size_t)b * 393216 + (type ? 163840 : 0) + n * 20480 + i * 20;
    float sc = type ? LOG2E : 1.0f;
    unsigned short* dst = (type ? Qb : Kb) + ((size_t)bn * 1024 + i) * 32;
    bf16x8 v[4] = {{}, {}, {}, {}};
    #pragma unroll
    for (int d = 0; d < 20; ++d) v[d >> 3][d & 7] = (short)f2bf(src[d] * sc);
    #pragma unroll
    for (int j = 0; j < 4; ++j) *(bf16x8*)&dst[j * 8] = v[j];
}

// ---- pack V -> Vt bf16 [bn][16 rows][1024 keys]: rows 0..7 = V^T, row 8 = ones ----
__global__ __launch_bounds__(256) void pack_vt_kernel(
    const float* __restrict__ kqv, unsigned short* __restrict__ Vt)
{
    int t = blockIdx.x * 256 + threadIdx.x;        // 64*16*1024 = 1048576
    int bn = t >> 14;
    int r = (t >> 10) & 15;
    int key = t & 1023;
    int b = bn >> 3, n = bn & 7;
    unsigned short o;
    if (r < 8)      o = f2bf(kqv[(size_t)b * 393216 + 327680 + n * 8192 + key * 8 + r]);
    else if (r == 8) o = 0x3F80;                   // bf16(1.0) -> lsum row
    else            o = 0;
    Vt[(size_t)t] = o;
}

// ---------------- head-sum of q: qsum[b][s][d] = sum_n q[b][n*20480 + s*20 + d] ----
__global__ void qsum_kernel(const float* __restrict__ kqv, float* __restrict__ qsum)
{
    int idx = blockIdx.x * 256 + threadIdx.x;   // 8 * 20480 = 163840
    int b = idx / 20480, t = idx - b * 20480;
    const float* qb = kqv + (size_t)b * 393216 + 163840 + t;
    float s = 0.0f;
    #pragma unroll
    for (int n = 0; n < 8; ++n) s += qb[(size_t)n * 20480];
    qsum[idx] = s;
}

// ---------------- rel logits (relative coords), scaled by LOG2E -------------------
__global__ void rel_kernel(const float* __restrict__ qsum,
    const float* __restrict__ rel_h, const float* __restrict__ rel_w,
    float* __restrict__ Rh, float* __restrict__ Rw)
{
    int idx = blockIdx.x * 256 + threadIdx.x;   // 8 * 1024 * 63 = 516096
    int b = idx / 64512, rem = idx - b * 64512;
    int s = rem / 63, mm = rem - s * 63;
    int y = s >> 5, x = s & 31;
    const float* qrow = qsum + (size_t)b * 20480 + s * 20;
    const float* rh = rel_h + mm * 20;
    const float* rw = rel_w + mm * 20;
    float sh = 0.0f, sw = 0.0f;
    #pragma unroll
    for (int d = 0; d < 20; ++d) {
        float qv = qrow[d];
        sh += qv * rh[d];
        sw += qv * rw[d];
    }
    Rw[(size_t)b * 64512 + s * 63 + mm] = sw * LOG2E;            // [b][y*32+x][m]
    Rh[(size_t)b * 64512 + (x * 32 + y) * 63 + mm] = sh * LOG2E; // [b][x*32+y][m]
}

// ---------------- MFMA flash attention: QK^T and PV both on matrix pipe ----------
// S^T = mfma(K,Q): lane (ql,g) holds logits for query ql, keys {16jj+4g+r}.
// P routed through per-wave LDS tile [q][key] -> B-frag of O^T = mfma(V^T, P^T).
// lsum via ones-row 8 of V^T (accumulates with identical rescaling).
__global__ __launch_bounds__(256, 4) void attn_mfma_kernel(
    const unsigned short* __restrict__ Qb, const unsigned short* __restrict__ Kb,
    const unsigned short* __restrict__ Vt, const float* __restrict__ Rh,
    const float* __restrict__ Rw, float* __restrict__ attnout)
{
    const int bn = blockIdx.y;                    // b*8+n
    const int b = bn >> 3;
    const int i0 = blockIdx.x * 64;
    const int tid = threadIdx.x;
    const int lane = tid & 63, w = tid >> 6;

    __shared__ float RhS[64][33];
    __shared__ float RwS[64][33];
    __shared__ unsigned short Pl[4][16][72];      // per-wave P^T tile, stride 144 B
    {
        int q = tid & 63, seg = tid >> 6;
        int i = i0 + q, y1 = i >> 5, x1 = i & 31;
        const float* rh = Rh + (size_t)b * 64512 + (x1 * 32 + y1) * 63 + 31 - y1 + seg * 8;
        const float* rw = Rw + (size_t)b * 64512 + i * 63 + 31 - x1 + seg * 8;
        #pragma unroll
        for (int j = 0; j < 8; ++j) {
            RhS[q][seg * 8 + j] = rh[j];
            RwS[q][seg * 8 + j] = rw[j];
        }
    }
    __syncthreads();

    const int ql = lane & 15, g = lane >> 4;
    const int qw = i0 + w * 16;

    bf16x8 qf = *(const bf16x8*)&Qb[((size_t)bn * 1024 + qw + ql) * 32 + g * 8];
    const unsigned short* kp = Kb + ((size_t)bn * 1024 + ql) * 32 + g * 8;
    const size_t vbase = ((size_t)bn * 16 + ql) * 1024;   // lane&15 doubles as dv row

    const float* rhrow = &RhS[w * 16 + ql][0];
    float rwA[4], rwB[4];
    #pragma unroll
    for (int r = 0; r < 4; ++r) {
        rwA[r] = RwS[w * 16 + ql][4 * g + r];
        rwB[r] = RwS[w * 16 + ql][16 + 4 * g + r];
    }

    float m = -1e30f;
    f32x4 oaccT = {};                              // O^T rows g*4+r (row 8 = lsum)

    #pragma unroll 2
    for (int kt = 0; kt < 16; ++kt) {
        bf16x8 k0 = *(const bf16x8*)&kp[0 * 512];
        bf16x8 k1 = *(const bf16x8*)&kp[1 * 512];
        bf16x8 k2 = *(const bf16x8*)&kp[2 * 512];
        bf16x8 k3 = *(const bf16x8*)&kp[3 * 512];
        f32x4 s0 = {}, s1 = {}, s2 = {}, s3 = {};
        s0 = __builtin_amdgcn_mfma_f32_16x16x32_bf16(k0, qf, s0, 0, 0, 0);
        s1 = __builtin_amdgcn_mfma_f32_16x16x32_bf16(k1, qf, s1, 0, 0, 0);
        s2 = __builtin_amdgcn_mfma_f32_16x16x32_bf16(k2, qf, s2, 0, 0, 0);
        s3 = __builtin_amdgcn_mfma_f32_16x16x32_bf16(k3, qf, s3, 0, 0, 0);

        float rh0 = rhrow[2 * kt];
        float rh1 = rhrow[2 * kt + 1];
        float lg[16];
        #pragma unroll
        for (int r = 0; r < 4; ++r) {
            lg[0 + r]  = s0[r] + (rh0 + rwA[r]);
            lg[4 + r]  = s1[r] + (rh0 + rwB[r]);
            lg[8 + r]  = s2[r] + (rh1 + rwA[r]);
            lg[12 + r] = s3[r] + (rh1 + rwB[r]);
        }
        float t0 = fmaxf(fmaxf(lg[0], lg[1]), fmaxf(lg[2], lg[3]));
        float t1 = fmaxf(fmaxf(lg[4], lg[5]), fmaxf(lg[6], lg[7]));
        float t2 = fmaxf(fmaxf(lg[8], lg[9]), fmaxf(lg[10], lg[11]));
        float t3 = fmaxf(fmaxf(lg[12], lg[13]), fmaxf(lg[14], lg[15]));
        float tmax = fmaxf(fmaxf(t0, t1), fmaxf(t2, t3));
        tmax = fmaxf(tmax, __shfl_xor(tmax, 16, 64));   // query-uniform tile max
        tmax = fmaxf(tmax, __shfl_xor(tmax, 32, 64));
        float mn = fmaxf(m, tmax);
        float sc = exp2f(m - mn);
        m = mn;
        oaccT *= sc;

        // P -> bf16 -> per-wave LDS [q][key]
        #pragma unroll
        for (int jj = 0; jj < 4; ++jj) {
            float p0 = exp2f(lg[jj * 4 + 0] - mn);
            float p1 = exp2f(lg[jj * 4 + 1] - mn);
            float p2 = exp2f(lg[jj * 4 + 2] - mn);
            float p3 = exp2f(lg[jj * 4 + 3] - mn);
            int key = jj * 16 + 4 * g;
            *(unsigned*)&Pl[w][ql][key]     = cvt_pk_bf16(p0, p1);
            *(unsigned*)&Pl[w][ql][key + 2] = cvt_pk_bf16(p2, p3);
        }

        // O^T += V^T(keys) @ P^T
        #pragma unroll
        for (int half = 0; half < 2; ++half) {
            bf16x8 vfr = *(const bf16x8*)&Vt[vbase + kt * 64 + half * 32 + g * 8];
            bf16x8 pfr = *(const bf16x8*)&Pl[w][ql][half * 32 + g * 8];
            oaccT = __builtin_amdgcn_mfma_f32_16x16x32_bf16(vfr, pfr, oaccT, 0, 0, 0);
        }
        kp += 2048;                                // 64 keys * 32 elems
    }

    float lsum = __shfl(oaccT[0], 32 + ql, 64);    // row 8 lives in lane g=2, reg 0
    float inv = 1.0f / lsum;
    if (g < 2) {
        float4 o = {oaccT[0] * inv, oaccT[1] * inv, oaccT[2] * inv, oaccT[3] * inv};
        *(float4*)&attnout[((size_t)bn * 1024 + qw + ql) * 8 + g * 4] = o;
    }
}

// ---------------- attn 1x1 conv (64->64) into output channels 192..255 ------------
__global__ __launch_bounds__(256) void attn_out_conv_kernel(
    const float* __restrict__ attn, const float* __restrict__ W,
    const float* __restrict__ bias, float* __restrict__ out)
{
    const int b  = blockIdx.z;
    const int oc = blockIdx.y;
    const int s  = blockIdx.x * 256 + threadIdx.x;
    const float* ab = attn + (size_t)b * 65536;
    float sum = bias[oc];
    #pragma unroll
    for (int c = 0; c < 64; ++c)
        sum += W[oc * 64 + c] * ab[(size_t)c * 1024 + s];
    out[(size_t)b * 262144 + (size_t)(192 + oc) * 1024 + s] = sum;
}

extern "C" void kernel_launch(void* const* d_in, const int* in_sizes, int n_in,
                              void* d_out, int out_size, void* d_ws, size_t ws_size,
                              hipStream_t stream)
{
    const float* x          = (const float*)d_in[0];
    const float* kqv_w      = (const float*)d_in[1];
    const float* kqv_b      = (const float*)d_in[2];
    const float* conv_out_w = (const float*)d_in[3];
    const float* conv_out_b = (const float*)d_in[4];
    const float* attn_w     = (const float*)d_in[5];
    const float* attn_b     = (const float*)d_in[6];
    const float* rel_h      = (const float*)d_in[7];
    const float* rel_w      = (const float*)d_in[8];
    float* out = (float*)d_out;
    float* ws  = (float*)d_ws;

    float* ws_kqv  = ws;                   // 3,145,728 f32
    float* ws_qsum = ws + 3145728;         //   163,840
    float* ws_rw   = ws + 3309568;         //   516,096
    float* ws_rh   = ws + 3825664;         //   516,096
    float* ws_attn = ws + 4341760;         //   524,288
    unsigned short* Qb = (unsigned short*)(ws + 4866048);  // 2,097,152 u16 (4 MB)
    unsigned short* Kb = (unsigned short*)(ws + 5914624);  // 2,097,152 u16 (4 MB)
    unsigned short* Vt = (unsigned short*)(ws + 6963200);  // 1,048,576 u16 (2 MB)
    // total: 7,487,488 f32 = 29.95 MB

    // Transient aliases (dead before their hosts are written):
    unsigned short* Xt = (unsigned short*)(ws + 4866048);     // 4.73 MB over Qb/Kb head
    unsigned short* Wp = (unsigned short*)ws_attn;            // 884,736 B
    unsigned short* Wq = (unsigned short*)(ws_attn + 221184); // 196,608 B

    pack_xt_kernel   <<<1156, 256, 0, stream>>>(x, Xt);
    pack_wconv_kernel<<< 216, 256, 0, stream>>>(conv_out_w, Wp);
    pack_wkqv_kernel <<<  48, 256, 0, stream>>>(kqv_w, Wq);
    mfma_kqv_kernel    <<<dim3(16, 6, 8), 256, 0, stream>>>(Wq, Xt, kqv_b, ws_kqv);
    mfma_conv3x3_kernel<<<dim3(16, 3, 8), 256, 0, stream>>>(Wp, Xt, conv_out_b, out);
    pack_qk_kernel<<<512, 256, 0, stream>>>(ws_kqv, Kb, Qb);   // after Xt consumers
    pack_vt_kernel<<<4096, 256, 0, stream>>>(ws_kqv, Vt);
    qsum_kernel<<<640, 256, 0, stream>>>(ws_kqv, ws_qsum);
    rel_kernel <<<2016, 256, 0, stream>>>(ws_qsum, rel_h, rel_w, ws_rh, ws_rw);
    attn_mfma_kernel<<<dim3(16, 64), 256, 0, stream>>>(Qb, Kb, Vt, ws_rh, ws_rw, ws_attn);
    attn_out_conv_kernel<<<dim3(4, 64, 8), 256, 0, stream>>>(ws_attn, attn_w, attn_b, out);
}

// Round 6
// 133.336 us; speedup vs baseline: 5.0451x; 1.0083x over previous
//
#include <hip/hip_runtime.h>

// Problem constants: B=8, C=256, H=W=32, NH=8, DK=160, DV=64, DKH=20, DVH=8
constexpr float QSCALE = 0.22360679774997896f; // 1/sqrt(20)
constexpr float LOG2E  = 1.4426950408889634f;

typedef __attribute__((ext_vector_type(8))) short bf16x8;
typedef __attribute__((ext_vector_type(4))) float f32x4;

__device__ __forceinline__ unsigned short f2bf(float f) {
    unsigned u = __float_as_uint(f);
    u = (u + 0x7FFFu + ((u >> 16) & 1u)) >> 16;   // RNE
    return (unsigned short)u;
}

__device__ __forceinline__ unsigned cvt_pk_bf16(float lo, float hi) {
    unsigned r;
    asm("v_cvt_pk_bf16_f32 %0, %1, %2" : "=v"(r) : "v"(lo), "v"(hi));
    return r;
}

// ---- pack x (f32 NCHW) -> Xt bf16 [b][(y+1)*34+(x+1)][256ch], zero-padded halo ----
__global__ __launch_bounds__(256) void pack_xt_kernel(
    const float* __restrict__ X, unsigned short* __restrict__ Xt)
{
    int t = blockIdx.x * 256 + threadIdx.x;        // 8*1156*32 = 295936
    int b = t / 36992, rem = t - b * 36992;
    int spad = rem >> 5, cc = rem & 31;
    int yp = spad / 34, xp = spad - yp * 34;
    bf16x8 v = {};
    if (yp >= 1 && yp <= 32 && xp >= 1 && xp <= 32) {
        const float* src = X + (size_t)b * 262144 + (size_t)(cc * 8) * 1024
                             + (yp - 1) * 32 + (xp - 1);
        #pragma unroll
        for (int j = 0; j < 8; ++j) v[j] = (short)f2bf(src[(size_t)j * 1024]);
    }
    *(bf16x8*)&Xt[((size_t)b * 1156 + spad) * 256 + cc * 8] = v;
}

// ---- pack conv_out_w (OIHW f32) -> fragment-order bf16, K reordered k'=r*256+c ----
__global__ __launch_bounds__(256) void pack_wconv_kernel(
    const float* __restrict__ W, unsigned short* __restrict__ Wp)
{
    int t = blockIdx.x * 256 + threadIdx.x;        // 3*72*4*64 = 55296
    int l = t & 63;
    int rb = (t >> 6) & 3;
    int ks = (t >> 8) % 72;
    int ot = t / 18432;
    int oc = ot * 64 + rb * 16 + (l & 15);
    int kbase = ks * 32 + (l >> 4) * 8;
    bf16x8 v;
    #pragma unroll
    for (int j = 0; j < 8; ++j) {
        int kp = kbase + j;
        int r = kp >> 8, c = kp & 255;             // k' = r*256 + c
        v[j] = (short)f2bf(W[((size_t)oc * 256 + c) * 9 + r]);
    }
    *(bf16x8*)&Wp[(size_t)t * 8] = v;
}

// ---- pack kqv_w -> fragment-order bf16 (QSCALE folded into q rows) ----
__global__ __launch_bounds__(256) void pack_wkqv_kernel(
    const float* __restrict__ W, unsigned short* __restrict__ Wq)
{
    int t = blockIdx.x * 256 + threadIdx.x;        // 6*8*4*64 = 12288
    int l = t & 63;
    int rb = (t >> 6) & 3;
    int ks = (t >> 8) & 7;
    int ot = t / 2048;
    int oc = ot * 64 + rb * 16 + (l & 15);
    float sc = (oc >= 160 && oc < 320) ? QSCALE : 1.0f;
    int kbase = ks * 32 + (l >> 4) * 8;
    bf16x8 v;
    #pragma unroll
    for (int j = 0; j < 8; ++j)
        v[j] = (short)f2bf(W[(size_t)oc * 256 + kbase + j] * sc);
    *(bf16x8*)&Wq[(size_t)t * 8] = v;
}

// ---- fused conv3x3 + kqv MFMA GEMM with LDS window staging --------------------
// blockIdx.y 0..2: conv oc-tiles (out ch 0..191); 3..8: kqv oc-tiles (384 ch).
// Per block: output spatial tile of 64 (2 y-rows), padded window 4x34 rows.
// K staged per 32-ch chunk into LDS (72B-padded rows), double-buffered.
__global__ __launch_bounds__(256) void mfma_fused_gemm_kernel(
    const unsigned short* __restrict__ Wp, const unsigned short* __restrict__ Wq,
    const unsigned short* __restrict__ Xt,
    const float* __restrict__ cbias, const float* __restrict__ qbias,
    float* __restrict__ out, float* __restrict__ kqv)
{
    const int b  = blockIdx.z;
    const int ty = blockIdx.y;                    // 0..8
    const int s0 = blockIdx.x * 64;
    const int Y  = blockIdx.x * 2;                // first output y-row
    const int tid = threadIdx.x;
    const int lane = tid & 63, w = tid >> 6;
    const int wr = w >> 1, wc = w & 1;
    const int kc = lane >> 4, ln = lane & 15;
    const bool isconv = ty < 3;

    __shared__ unsigned short Wnd[2][136 * 36];   // 4x34 rows x (32ch + 4 pad) bf16

    const unsigned short* xb = Xt + (size_t)b * 1156 * 256;

    // staging geometry: 544 quarter-rows (136 rows x 4 x 16B)
    const int r1 = tid >> 2, q = tid & 3;
    const int r2 = r1 + 64, r3 = r1 + 128;        // r3 valid only for tid<32
    const int g1 = ((Y + r1 / 34) * 34 + (r1 % 34)) * 256 + q * 8;
    const int g2 = ((Y + r2 / 34) * 34 + (r2 % 34)) * 256 + q * 8;
    const int g3 = ((Y + r3 / 34) * 34 + (r3 % 34)) * 256 + q * 8;
    const int d1 = r1 * 36 + q * 8;
    const int d2 = r2 * 36 + q * 8;
    const int d3 = r3 * 36 + q * 8;

    size_t aoff0;
    if (isconv) aoff0 = ((size_t)(ty * 288 + wr * 2) * 64 + lane) * 8;
    else        aoff0 = ((size_t)((ty - 3) * 32 + wr * 2) * 64 + lane) * 8;
    const size_t aoff1 = aoff0 + 512;

    const int bb = (wc * 34 + ln) * 36 + kc * 8;  // B-frag LDS base (shorts)

    f32x4 acc00 = {}, acc01 = {}, acc10 = {}, acc11 = {};

    // prologue: stage chunk 0
    {
        bf16x8 v1 = *(const bf16x8*)&xb[g1];
        bf16x8 v2 = *(const bf16x8*)&xb[g2];
        *(bf16x8*)&Wnd[0][d1] = v1;
        *(bf16x8*)&Wnd[0][d2] = v2;
        if (tid < 32) {
            bf16x8 v3 = *(const bf16x8*)&xb[g3];
            *(bf16x8*)&Wnd[0][d3] = v3;
        }
    }
    __syncthreads();

    for (int cc = 0; cc < 8; ++cc) {
        // issue next chunk's global loads early (hide under compute)
        bf16x8 v1, v2, v3;
        if (cc < 7) {
            int co = (cc + 1) * 32;
            v1 = *(const bf16x8*)&xb[g1 + co];
            v2 = *(const bf16x8*)&xb[g2 + co];
            if (tid < 32) v3 = *(const bf16x8*)&xb[g3 + co];
        }

        const unsigned short* Wc = Wnd[cc & 1];
        if (isconv) {
            #pragma unroll
            for (int r = 0; r < 9; ++r) {
                const int ky = r / 3, kx = r % 3;
                const int ro = (ky * 34 + kx) * 36;
                bf16x8 a0 = *(const bf16x8*)&Wp[aoff0 + (size_t)(r * 8 + cc) * 2048];
                bf16x8 a1 = *(const bf16x8*)&Wp[aoff1 + (size_t)(r * 8 + cc) * 2048];
                bf16x8 b0 = *(const bf16x8*)&Wc[bb + ro];
                bf16x8 b1 = *(const bf16x8*)&Wc[bb + ro + 16 * 36];
                acc00 = __builtin_amdgcn_mfma_f32_16x16x32_bf16(a0, b0, acc00, 0, 0, 0);
                acc01 = __builtin_amdgcn_mfma_f32_16x16x32_bf16(a0, b1, acc01, 0, 0, 0);
                acc10 = __builtin_amdgcn_mfma_f32_16x16x32_bf16(a1, b0, acc10, 0, 0, 0);
                acc11 = __builtin_amdgcn_mfma_f32_16x16x32_bf16(a1, b1, acc11, 0, 0, 0);
            }
        } else {
            const int ro = 35 * 36;                // (ky=1)*34 + (kx=1)
            bf16x8 a0 = *(const bf16x8*)&Wq[aoff0 + (size_t)cc * 2048];
            bf16x8 a1 = *(const bf16x8*)&Wq[aoff1 + (size_t)cc * 2048];
            bf16x8 b0 = *(const bf16x8*)&Wc[bb + ro];
            bf16x8 b1 = *(const bf16x8*)&Wc[bb + ro + 16 * 36];
            acc00 = __builtin_amdgcn_mfma_f32_16x16x32_bf16(a0, b0, acc00, 0, 0, 0);
            acc01 = __builtin_amdgcn_mfma_f32_16x16x32_bf16(a0, b1, acc01, 0, 0, 0);
            acc10 = __builtin_amdgcn_mfma_f32_16x16x32_bf16(a1, b0, acc10, 0, 0, 0);
            acc11 = __builtin_amdgcn_mfma_f32_16x16x32_bf16(a1, b1, acc11, 0, 0, 0);
        }

        if (cc < 7) {
            unsigned short* Wn = Wnd[(cc + 1) & 1];
            *(bf16x8*)&Wn[d1] = v1;
            *(bf16x8*)&Wn[d2] = v2;
            if (tid < 32) *(bf16x8*)&Wn[d3] = v3;
        }
        __syncthreads();
    }

    const int scol = s0 + wc * 32 + ln;
    if (isconv) {
        const int ocb = ty * 64 + wr * 32;
        float* ob = out + (size_t)b * 262144;
        #pragma unroll
        for (int r = 0; r < 4; ++r) {
            int oc0 = ocb + kc * 4 + r;
            float b0v = cbias[oc0];
            ob[(size_t)oc0 * 1024 + scol]      = acc00[r] + b0v;
            ob[(size_t)oc0 * 1024 + scol + 16] = acc01[r] + b0v;
            int oc1 = oc0 + 16;
            float b1v = cbias[oc1];
            ob[(size_t)oc1 * 1024 + scol]      = acc10[r] + b1v;
            ob[(size_t)oc1 * 1024 + scol + 16] = acc11[r] + b1v;
        }
    } else {
        const int ocb = (ty - 3) * 64 + wr * 32;
        float* ob = kqv + (size_t)b * 393216;
        #pragma unroll
        for (int r = 0; r < 4; ++r) {
            int oc0 = ocb + kc * 4 + r;
            float b0v = qbias[oc0] * ((oc0 >= 160 && oc0 < 320) ? QSCALE : 1.0f);
            ob[(size_t)oc0 * 1024 + scol]      = acc00[r] + b0v;
            ob[(size_t)oc0 * 1024 + scol + 16] = acc01[r] + b0v;
            int oc1 = oc0 + 16;
            float b1v = qbias[oc1] * ((oc1 >= 160 && oc1 < 320) ? QSCALE : 1.0f);
            ob[(size_t)oc1 * 1024 + scol]      = acc10[r] + b1v;
            ob[(size_t)oc1 * 1024 + scol + 16] = acc11[r] + b1v;
        }
    }
}

// ---- pack q/k (f32 kqv flat) -> bf16 [bn*1024+i][32] zero-padded; q scaled LOG2E ----
__global__ __launch_bounds__(256) void pack_qk_kernel(
    const float* __restrict__ kqv, unsigned short* __restrict__ Kb,
    unsigned short* __restrict__ Qb)
{
    int idx = blockIdx.x * 256 + threadIdx.x;      // 131072
    int type = idx >> 16;                          // 0: K, 1: Q
    int r = idx & 65535;
    int bn = r >> 10, i = r & 1023;
    int b = bn >> 3, n = bn & 7;
    const float* src = kqv + (size_t)b * 393216 + (type ? 163840 : 0) + n * 20480 + i * 20;
    float sc = type ? LOG2E : 1.0f;
    unsigned short* dst = (type ? Qb : Kb) + ((size_t)bn * 1024 + i) * 32;
    bf16x8 v[4] = {{}, {}, {}, {}};
    #pragma unroll
    for (int d = 0; d < 20; ++d) v[d >> 3][d & 7] = (short)f2bf(src[d] * sc);
    #pragma unroll
    for (int j = 0; j < 4; ++j) *(bf16x8*)&dst[j * 8] = v[j];
}

// ---- pack V -> Vt bf16 [bn][16 rows][1024 keys]: rows 0..7 = V^T, row 8 = ones ----
__global__ __launch_bounds__(256) void pack_vt_kernel(
    const float* __restrict__ kqv, unsigned short* __restrict__ Vt)
{
    int t = blockIdx.x * 256 + threadIdx.x;        // 64*16*1024 = 1048576
    int bn = t >> 14;
    int r = (t >> 10) & 15;
    int key = t & 1023;
    int b = bn >> 3, n = bn & 7;
    unsigned short o;
    if (r < 8)      o = f2bf(kqv[(size_t)b * 393216 + 327680 + n * 8192 + key * 8 + r]);
    else if (r == 8) o = 0x3F80;                   // bf16(1.0) -> lsum row
    else            o = 0;
    Vt[(size_t)t] = o;
}

// ---------------- head-sum of q: qsum[b][s][d] = sum_n q[b][n*20480 + s*20 + d] ----
__global__ void qsum_kernel(const float* __restrict__ kqv, float* __restrict__ qsum)
{
    int idx = blockIdx.x * 256 + threadIdx.x;   // 8 * 20480 = 163840
    int b = idx / 20480, t = idx - b * 20480;
    const float* qb = kqv + (size_t)b * 393216 + 163840 + t;
    float s = 0.0f;
    #pragma unroll
    for (int n = 0; n < 8; ++n) s += qb[(size_t)n * 20480];
    qsum[idx] = s;
}

// ---------------- rel logits (relative coords), scaled by LOG2E -------------------
__global__ void rel_kernel(const float* __restrict__ qsum,
    const float* __restrict__ rel_h, const float* __restrict__ rel_w,
    float* __restrict__ Rh, float* __restrict__ Rw)
{
    int idx = blockIdx.x * 256 + threadIdx.x;   // 8 * 1024 * 63 = 516096
    int b = idx / 64512, rem = idx - b * 64512;
    int s = rem / 63, mm = rem - s * 63;
    int y = s >> 5, x = s & 31;
    const float* qrow = qsum + (size_t)b * 20480 + s * 20;
    const float* rh = rel_h + mm * 20;
    const float* rw = rel_w + mm * 20;
    float sh = 0.0f, sw = 0.0f;
    #pragma unroll
    for (int d = 0; d < 20; ++d) {
        float qv = qrow[d];
        sh += qv * rh[d];
        sw += qv * rw[d];
    }
    Rw[(size_t)b * 64512 + s * 63 + mm] = sw * LOG2E;            // [b][y*32+x][m]
    Rh[(size_t)b * 64512 + (x * 32 + y) * 63 + mm] = sh * LOG2E; // [b][x*32+y][m]
}

// ---------------- MFMA flash attention: QK^T and PV both on matrix pipe ----------
__global__ __launch_bounds__(256, 4) void attn_mfma_kernel(
    const unsigned short* __restrict__ Qb, const unsigned short* __restrict__ Kb,
    const unsigned short* __restrict__ Vt, const float* __restrict__ Rh,
    const float* __restrict__ Rw, float* __restrict__ attnout)
{
    const int bn = blockIdx.y;                    // b*8+n
    const int b = bn >> 3;
    const int i0 = blockIdx.x * 64;
    const int tid = threadIdx.x;
    const int lane = tid & 63, w = tid >> 6;

    __shared__ float RhS[64][33];
    __shared__ float RwS[64][33];
    __shared__ unsigned short Pl[4][16][72];      // per-wave P^T tile, stride 144 B
    {
        int q = tid & 63, seg = tid >> 6;
        int i = i0 + q, y1 = i >> 5, x1 = i & 31;
        const float* rh = Rh + (size_t)b * 64512 + (x1 * 32 + y1) * 63 + 31 - y1 + seg * 8;
        const float* rw = Rw + (size_t)b * 64512 + i * 63 + 31 - x1 + seg * 8;
        #pragma unroll
        for (int j = 0; j < 8; ++j) {
            RhS[q][seg * 8 + j] = rh[j];
            RwS[q][seg * 8 + j] = rw[j];
        }
    }
    __syncthreads();

    const int ql = lane & 15, g = lane >> 4;
    const int qw = i0 + w * 16;

    bf16x8 qf = *(const bf16x8*)&Qb[((size_t)bn * 1024 + qw + ql) * 32 + g * 8];
    const unsigned short* kp = Kb + ((size_t)bn * 1024 + ql) * 32 + g * 8;
    const size_t vbase = ((size_t)bn * 16 + ql) * 1024;   // lane&15 doubles as dv row

    const float* rhrow = &RhS[w * 16 + ql][0];
    float rwA[4], rwB[4];
    #pragma unroll
    for (int r = 0; r < 4; ++r) {
        rwA[r] = RwS[w * 16 + ql][4 * g + r];
        rwB[r] = RwS[w * 16 + ql][16 + 4 * g + r];
    }

    float m = -1e30f;
    f32x4 oaccT = {};                              // O^T rows g*4+r (row 8 = lsum)

    #pragma unroll 2
    for (int kt = 0; kt < 16; ++kt) {
        bf16x8 k0 = *(const bf16x8*)&kp[0 * 512];
        bf16x8 k1 = *(const bf16x8*)&kp[1 * 512];
        bf16x8 k2 = *(const bf16x8*)&kp[2 * 512];
        bf16x8 k3 = *(const bf16x8*)&kp[3 * 512];
        f32x4 s0 = {}, s1 = {}, s2 = {}, s3 = {};
        s0 = __builtin_amdgcn_mfma_f32_16x16x32_bf16(k0, qf, s0, 0, 0, 0);
        s1 = __builtin_amdgcn_mfma_f32_16x16x32_bf16(k1, qf, s1, 0, 0, 0);
        s2 = __builtin_amdgcn_mfma_f32_16x16x32_bf16(k2, qf, s2, 0, 0, 0);
        s3 = __builtin_amdgcn_mfma_f32_16x16x32_bf16(k3, qf, s3, 0, 0, 0);

        float rh0 = rhrow[2 * kt];
        float rh1 = rhrow[2 * kt + 1];
        float lg[16];
        #pragma unroll
        for (int r = 0; r < 4; ++r) {
            lg[0 + r]  = s0[r] + (rh0 + rwA[r]);
            lg[4 + r]  = s1[r] + (rh0 + rwB[r]);
            lg[8 + r]  = s2[r] + (rh1 + rwA[r]);
            lg[12 + r] = s3[r] + (rh1 + rwB[r]);
        }
        float t0 = fmaxf(fmaxf(lg[0], lg[1]), fmaxf(lg[2], lg[3]));
        float t1 = fmaxf(fmaxf(lg[4], lg[5]), fmaxf(lg[6], lg[7]));
        float t2 = fmaxf(fmaxf(lg[8], lg[9]), fmaxf(lg[10], lg[11]));
        float t3 = fmaxf(fmaxf(lg[12], lg[13]), fmaxf(lg[14], lg[15]));
        float tmax = fmaxf(fmaxf(t0, t1), fmaxf(t2, t3));
        tmax = fmaxf(tmax, __shfl_xor(tmax, 16, 64));   // query-uniform tile max
        tmax = fmaxf(tmax, __shfl_xor(tmax, 32, 64));
        float mn = fmaxf(m, tmax);
        float sc = exp2f(m - mn);
        m = mn;
        oaccT *= sc;

        // P -> bf16 -> per-wave LDS [q][key]
        #pragma unroll
        for (int jj = 0; jj < 4; ++jj) {
            float p0 = exp2f(lg[jj * 4 + 0] - mn);
            float p1 = exp2f(lg[jj * 4 + 1] - mn);
            float p2 = exp2f(lg[jj * 4 + 2] - mn);
            float p3 = exp2f(lg[jj * 4 + 3] - mn);
            int key = jj * 16 + 4 * g;
            *(unsigned*)&Pl[w][ql][key]     = cvt_pk_bf16(p0, p1);
            *(unsigned*)&Pl[w][ql][key + 2] = cvt_pk_bf16(p2, p3);
        }

        // O^T += V^T(keys) @ P^T
        #pragma unroll
        for (int half = 0; half < 2; ++half) {
            bf16x8 vfr = *(const bf16x8*)&Vt[vbase + kt * 64 + half * 32 + g * 8];
            bf16x8 pfr = *(const bf16x8*)&Pl[w][ql][half * 32 + g * 8];
            oaccT = __builtin_amdgcn_mfma_f32_16x16x32_bf16(vfr, pfr, oaccT, 0, 0, 0);
        }
        kp += 2048;                                // 64 keys * 32 elems
    }

    float lsum = __shfl(oaccT[0], 32 + ql, 64);    // row 8 lives in lane g=2, reg 0
    float inv = 1.0f / lsum;
    if (g < 2) {
        float4 o = {oaccT[0] * inv, oaccT[1] * inv, oaccT[2] * inv, oaccT[3] * inv};
        *(float4*)&attnout[((size_t)bn * 1024 + qw + ql) * 8 + g * 4] = o;
    }
}

// ---------------- attn 1x1 conv (64->64) into output channels 192..255 ------------
__global__ __launch_bounds__(256) void attn_out_conv_kernel(
    const float* __restrict__ attn, const float* __restrict__ W,
    const float* __restrict__ bias, float* __restrict__ out)
{
    const int b  = blockIdx.z;
    const int oc = blockIdx.y;
    const int s  = blockIdx.x * 256 + threadIdx.x;
    const float* ab = attn + (size_t)b * 65536;
    float sum = bias[oc];
    #pragma unroll
    for (int c = 0; c < 64; ++c)
        sum += W[oc * 64 + c] * ab[(size_t)c * 1024 + s];
    out[(size_t)b * 262144 + (size_t)(192 + oc) * 1024 + s] = sum;
}

extern "C" void kernel_launch(void* const* d_in, const int* in_sizes, int n_in,
                              void* d_out, int out_size, void* d_ws, size_t ws_size,
                              hipStream_t stream)
{
    const float* x          = (const float*)d_in[0];
    const float* kqv_w      = (const float*)d_in[1];
    const float* kqv_b      = (const float*)d_in[2];
    const float* conv_out_w = (const float*)d_in[3];
    const float* conv_out_b = (const float*)d_in[4];
    const float* attn_w     = (const float*)d_in[5];
    const float* attn_b     = (const float*)d_in[6];
    const float* rel_h      = (const float*)d_in[7];
    const float* rel_w      = (const float*)d_in[8];
    float* out = (float*)d_out;
    float* ws  = (float*)d_ws;

    float* ws_kqv  = ws;                   // 3,145,728 f32
    float* ws_qsum = ws + 3145728;         //   163,840
    float* ws_rw   = ws + 3309568;         //   516,096
    float* ws_rh   = ws + 3825664;         //   516,096
    float* ws_attn = ws + 4341760;         //   524,288
    unsigned short* Qb = (unsigned short*)(ws + 4866048);  // 2,097,152 u16 (4 MB)
    unsigned short* Kb = (unsigned short*)(ws + 5914624);  // 2,097,152 u16 (4 MB)
    unsigned short* Vt = (unsigned short*)(ws + 6963200);  // 1,048,576 u16 (2 MB)
    // total: 7,487,488 f32 = 29.95 MB

    // Transient aliases (dead before their hosts are written):
    unsigned short* Xt = (unsigned short*)(ws + 4866048);     // 4.73 MB over Qb/Kb head
    unsigned short* Wp = (unsigned short*)ws_attn;            // 884,736 B
    unsigned short* Wq = (unsigned short*)(ws_attn + 221184); // 196,608 B

    pack_xt_kernel   <<<1156, 256, 0, stream>>>(x, Xt);
    pack_wconv_kernel<<< 216, 256, 0, stream>>>(conv_out_w, Wp);
    pack_wkqv_kernel <<<  48, 256, 0, stream>>>(kqv_w, Wq);
    mfma_fused_gemm_kernel<<<dim3(16, 9, 8), 256, 0, stream>>>(
        Wp, Wq, Xt, conv_out_b, kqv_b, out, ws_kqv);
    pack_qk_kernel<<<512, 256, 0, stream>>>(ws_kqv, Kb, Qb);   // after Xt consumers
    pack_vt_kernel<<<4096, 256, 0, stream>>>(ws_kqv, Vt);
    qsum_kernel<<<640, 256, 0, stream>>>(ws_kqv, ws_qsum);
    rel_kernel <<<2016, 256, 0, stream>>>(ws_qsum, rel_h, rel_w, ws_rh, ws_rw);
    attn_mfma_kernel<<<dim3(16, 64), 256, 0, stream>>>(Qb, Kb, Vt, ws_rh, ws_rw, ws_attn);
    attn_out_conv_kernel<<<dim3(4, 64, 8), 256, 0, stream>>>(ws_attn, attn_w, attn_b, out);
}

// Round 7
// 129.262 us; speedup vs baseline: 5.2041x; 1.0315x over previous
//
#include <hip/hip_runtime.h>

// Problem constants: B=8, C=256, H=W=32, NH=8, DK=160, DV=64, DKH=20, DVH=8
constexpr float QSCALE = 0.22360679774997896f; // 1/sqrt(20)
constexpr float LOG2E  = 1.4426950408889634f;

typedef __attribute__((ext_vector_type(8))) short bf16x8;
typedef __attribute__((ext_vector_type(4))) float f32x4;

__device__ __forceinline__ unsigned short f2bf(float f) {
    unsigned u = __float_as_uint(f);
    u = (u + 0x7FFFu + ((u >> 16) & 1u)) >> 16;   // RNE
    return (unsigned short)u;
}

__device__ __forceinline__ unsigned cvt_pk_bf16(float lo, float hi) {
    unsigned r;
    asm("v_cvt_pk_bf16_f32 %0, %1, %2" : "=v"(r) : "v"(lo), "v"(hi));
    return r;
}

// ---- pack x -> Xt2 bf16 [b][chunk32(8)][spad(1156)][32ch], zero-padded halo ------
// Conv staging window (136 consecutive spad rows x 64B) is fully contiguous.
__global__ __launch_bounds__(256) void pack_xt2_kernel(
    const float* __restrict__ X, unsigned short* __restrict__ Xt2)
{
    int t = blockIdx.x * 256 + threadIdx.x;        // 8*8*4*1156 = 295936
    int b = t / 36992, rem = t - b * 36992;
    int chunk = rem / 4624; int rem2 = rem - chunk * 4624;
    int kc = rem2 / 1156;   int spad = rem2 - kc * 1156;
    int yp = spad / 34, xp = spad - yp * 34;
    bf16x8 v = {};
    if (yp >= 1 && yp <= 32 && xp >= 1 && xp <= 32) {
        const float* src = X + (size_t)b * 262144 + (size_t)(chunk * 32 + kc * 8) * 1024
                             + (yp - 1) * 32 + (xp - 1);
        #pragma unroll
        for (int j = 0; j < 8; ++j) v[j] = (short)f2bf(src[(size_t)j * 1024]);
    }
    *(bf16x8*)&Xt2[(((size_t)b * 8 + chunk) * 1156 + spad) * 32 + kc * 8] = v;
}

// ---- pack x -> Xq bf16 fragment-order [b][g16(64)][chunk(8)][lane(64)][8] --------
// Lane (kc,ln): ch = chunk*32 + kc*8 + j, spatial = g16*16 + ln. B-loads coalesce.
__global__ __launch_bounds__(256) void pack_xq_kernel(
    const float* __restrict__ X, unsigned short* __restrict__ Xq)
{
    int t = blockIdx.x * 256 + threadIdx.x;        // 8*64*8*64 = 262144
    int lane = t & 63;
    int chunk = (t >> 6) & 7;
    int g16 = (t >> 9) & 63;
    int b = t >> 15;
    int sp = g16 * 16 + (lane & 15);
    const float* src = X + (size_t)b * 262144
                         + (size_t)(chunk * 32 + (lane >> 4) * 8) * 1024 + sp;
    bf16x8 v;
    #pragma unroll
    for (int j = 0; j < 8; ++j) v[j] = (short)f2bf(src[(size_t)j * 1024]);
    *(bf16x8*)&Xq[(size_t)t * 8] = v;
}

// ---- pack conv_out_w (OIHW f32) -> fragment-order bf16, K reordered k'=r*256+c ----
__global__ __launch_bounds__(256) void pack_wconv_kernel(
    const float* __restrict__ W, unsigned short* __restrict__ Wp)
{
    int t = blockIdx.x * 256 + threadIdx.x;        // 3*72*4*64 = 55296
    int l = t & 63;
    int rb = (t >> 6) & 3;
    int ks = (t >> 8) % 72;
    int ot = t / 18432;
    int oc = ot * 64 + rb * 16 + (l & 15);
    int kbase = ks * 32 + (l >> 4) * 8;
    bf16x8 v;
    #pragma unroll
    for (int j = 0; j < 8; ++j) {
        int kp = kbase + j;
        int r = kp >> 8, c = kp & 255;             // k' = r*256 + c
        v[j] = (short)f2bf(W[((size_t)oc * 256 + c) * 9 + r]);
    }
    *(bf16x8*)&Wp[(size_t)t * 8] = v;
}

// ---- pack kqv_w -> fragment-order bf16 (QSCALE folded into q rows) ----
__global__ __launch_bounds__(256) void pack_wkqv_kernel(
    const float* __restrict__ W, unsigned short* __restrict__ Wq)
{
    int t = blockIdx.x * 256 + threadIdx.x;        // 6*8*4*64 = 12288
    int l = t & 63;
    int rb = (t >> 6) & 3;
    int ks = (t >> 8) & 7;
    int ot = t / 2048;
    int oc = ot * 64 + rb * 16 + (l & 15);
    float sc = (oc >= 160 && oc < 320) ? QSCALE : 1.0f;
    int kbase = ks * 32 + (l >> 4) * 8;
    bf16x8 v;
    #pragma unroll
    for (int j = 0; j < 8; ++j)
        v[j] = (short)f2bf(W[(size_t)oc * 256 + kbase + j] * sc);
    *(bf16x8*)&Wq[(size_t)t * 8] = v;
}

// ---- conv_out 3x3 MFMA implicit GEMM, LDS window staged from chunk-major Xt2 -----
__global__ __launch_bounds__(256) void mfma_conv_kernel(
    const unsigned short* __restrict__ Wp, const unsigned short* __restrict__ Xt2,
    const float* __restrict__ bias, float* __restrict__ out)
{
    const int b  = blockIdx.z;
    const int ot = blockIdx.y;                    // 0..2
    const int s0 = blockIdx.x * 64;
    const int Y  = blockIdx.x * 2;                // first output y-row
    const int tid = threadIdx.x;
    const int lane = tid & 63, w = tid >> 6;
    const int wr = w >> 1, wc = w & 1;
    const int kc = lane >> 4, ln = lane & 15;

    __shared__ unsigned short Wnd[2][136 * 36];   // 136 rows x (32ch + 4 pad)

    // per-chunk window: 136 consecutive spad rows x 32ch = 4352 shorts contiguous
    const size_t wbase = ((size_t)b * 8 * 1156 + Y * 34) * 32;  // + cc*1156*32
    const int f1 = tid, f2 = tid + 256, f3 = tid + 512;         // f3 if tid<32
    const int d1 = (f1 >> 2) * 36 + (f1 & 3) * 8;
    const int d2 = (f2 >> 2) * 36 + (f2 & 3) * 8;
    const int d3 = (f3 >> 2) * 36 + (f3 & 3) * 8;

    const size_t aoff0 = ((size_t)(ot * 288 + wr * 2) * 64 + lane) * 8;
    const size_t aoff1 = aoff0 + 512;
    const int bb = (wc * 34 + ln) * 36 + kc * 8;  // B-frag LDS base (shorts)

    f32x4 acc00 = {}, acc01 = {}, acc10 = {}, acc11 = {};

    {   // prologue: stage chunk 0
        const unsigned short* g = &Xt2[wbase];
        *(bf16x8*)&Wnd[0][d1] = *(const bf16x8*)&g[f1 * 8];
        *(bf16x8*)&Wnd[0][d2] = *(const bf16x8*)&g[f2 * 8];
        if (tid < 32) *(bf16x8*)&Wnd[0][d3] = *(const bf16x8*)&g[f3 * 8];
    }
    __syncthreads();

    for (int cc = 0; cc < 8; ++cc) {
        bf16x8 v1, v2, v3;
        if (cc < 7) {                              // issue next chunk's loads early
            const unsigned short* g = &Xt2[wbase + (size_t)(cc + 1) * 1156 * 32];
            v1 = *(const bf16x8*)&g[f1 * 8];
            v2 = *(const bf16x8*)&g[f2 * 8];
            if (tid < 32) v3 = *(const bf16x8*)&g[f3 * 8];
        }

        const unsigned short* Wc = Wnd[cc & 1];
        #pragma unroll
        for (int r = 0; r < 9; ++r) {
            const int ky = r / 3, kx = r % 3;
            const int ro = (ky * 34 + kx) * 36;
            bf16x8 a0 = *(const bf16x8*)&Wp[aoff0 + (size_t)(r * 8 + cc) * 2048];
            bf16x8 a1 = *(const bf16x8*)&Wp[aoff1 + (size_t)(r * 8 + cc) * 2048];
            bf16x8 b0 = *(const bf16x8*)&Wc[bb + ro];
            bf16x8 b1 = *(const bf16x8*)&Wc[bb + ro + 16 * 36];
            acc00 = __builtin_amdgcn_mfma_f32_16x16x32_bf16(a0, b0, acc00, 0, 0, 0);
            acc01 = __builtin_amdgcn_mfma_f32_16x16x32_bf16(a0, b1, acc01, 0, 0, 0);
            acc10 = __builtin_amdgcn_mfma_f32_16x16x32_bf16(a1, b0, acc10, 0, 0, 0);
            acc11 = __builtin_amdgcn_mfma_f32_16x16x32_bf16(a1, b1, acc11, 0, 0, 0);
        }

        if (cc < 7) {
            unsigned short* Wn = Wnd[(cc + 1) & 1];
            *(bf16x8*)&Wn[d1] = v1;
            *(bf16x8*)&Wn[d2] = v2;
            if (tid < 32) *(bf16x8*)&Wn[d3] = v3;
        }
        __syncthreads();
    }

    const int ocb = ot * 64 + wr * 32;
    const int scol = s0 + wc * 32 + ln;
    float* ob = out + (size_t)b * 262144;
    #pragma unroll
    for (int r = 0; r < 4; ++r) {
        int oc0 = ocb + kc * 4 + r;
        float b0v = bias[oc0];
        ob[(size_t)oc0 * 1024 + scol]      = acc00[r] + b0v;
        ob[(size_t)oc0 * 1024 + scol + 16] = acc01[r] + b0v;
        int oc1 = oc0 + 16;
        float b1v = bias[oc1];
        ob[(size_t)oc1 * 1024 + scol]      = acc10[r] + b1v;
        ob[(size_t)oc1 * 1024 + scol + 16] = acc11[r] + b1v;
    }
}

// ---- kqv 1x1 conv: LDS-free MFMA GEMM from fragment-order Xq ---------------------
__global__ __launch_bounds__(256) void mfma_kqv_kernel(
    const unsigned short* __restrict__ Wq, const unsigned short* __restrict__ Xq,
    const float* __restrict__ bias, float* __restrict__ kqv)
{
    const int b  = blockIdx.z;
    const int ot = blockIdx.y;                    // 0..5
    const int s0 = blockIdx.x * 64;
    const int tid = threadIdx.x;
    const int lane = tid & 63, w = tid >> 6;
    const int wr = w >> 1, wc = w & 1;
    const int kc = lane >> 4, ln = lane & 15;

    const size_t aoff0 = ((size_t)(ot * 32 + wr * 2) * 64 + lane) * 8;
    const size_t aoff1 = aoff0 + 512;
    const int g0 = blockIdx.x * 4 + wc * 2;       // 16-spatial group of b0
    const size_t xb0 = (((size_t)b * 64 + g0) * 8) * 512 + lane * 8;
    const size_t xb1 = xb0 + 4096;                // next g16 group (+16 spatial)

    f32x4 acc00 = {}, acc01 = {}, acc10 = {}, acc11 = {};

    #pragma unroll
    for (int cc = 0; cc < 8; ++cc) {
        bf16x8 a0 = *(const bf16x8*)&Wq[aoff0 + (size_t)cc * 2048];
        bf16x8 a1 = *(const bf16x8*)&Wq[aoff1 + (size_t)cc * 2048];
        bf16x8 b0 = *(const bf16x8*)&Xq[xb0 + (size_t)cc * 512];
        bf16x8 b1 = *(const bf16x8*)&Xq[xb1 + (size_t)cc * 512];
        acc00 = __builtin_amdgcn_mfma_f32_16x16x32_bf16(a0, b0, acc00, 0, 0, 0);
        acc01 = __builtin_amdgcn_mfma_f32_16x16x32_bf16(a0, b1, acc01, 0, 0, 0);
        acc10 = __builtin_amdgcn_mfma_f32_16x16x32_bf16(a1, b0, acc10, 0, 0, 0);
        acc11 = __builtin_amdgcn_mfma_f32_16x16x32_bf16(a1, b1, acc11, 0, 0, 0);
    }

    const int ocb = ot * 64 + wr * 32;
    const int scol = s0 + wc * 32 + ln;
    float* ob = kqv + (size_t)b * 393216;
    #pragma unroll
    for (int r = 0; r < 4; ++r) {
        int oc0 = ocb + kc * 4 + r;
        float b0v = bias[oc0] * ((oc0 >= 160 && oc0 < 320) ? QSCALE : 1.0f);
        ob[(size_t)oc0 * 1024 + scol]      = acc00[r] + b0v;
        ob[(size_t)oc0 * 1024 + scol + 16] = acc01[r] + b0v;
        int oc1 = oc0 + 16;
        float b1v = bias[oc1] * ((oc1 >= 160 && oc1 < 320) ? QSCALE : 1.0f);
        ob[(size_t)oc1 * 1024 + scol]      = acc10[r] + b1v;
        ob[(size_t)oc1 * 1024 + scol + 16] = acc11[r] + b1v;
    }
}

// ---- pack q/k (f32 kqv flat) -> bf16 [bn*1024+i][32] zero-padded; q scaled LOG2E ----
__global__ __launch_bounds__(256) void pack_qk_kernel(
    const float* __restrict__ kqv, unsigned short* __restrict__ Kb,
    unsigned short* __restrict__ Qb)
{
    int idx = blockIdx.x * 256 + threadIdx.x;      // 131072
    int type = idx >> 16;                          // 0: K, 1: Q
    int r = idx & 65535;
    int bn = r >> 10, i = r & 1023;
    int b = bn >> 3, n = bn & 7;
    const float* src = kqv + (size_t)b * 393216 + (type ? 163840 : 0) + n * 20480 + i * 20;
    float sc = type ? LOG2E : 1.0f;
    unsigned short* dst = (type ? Qb : Kb) + ((size_t)bn * 1024 + i) * 32;
    bf16x8 v[4] = {{}, {}, {}, {}};
    #pragma unroll
    for (int d = 0; d < 20; ++d) v[d >> 3][d & 7] = (short)f2bf(src[d] * sc);
    #pragma unroll
    for (int j = 0; j < 4; ++j) *(bf16x8*)&dst[j * 8] = v[j];
}

// ---- pack V -> Vt bf16 [bn][16 rows][1024 keys]: rows 0..7 = V^T, row 8 = ones ----
__global__ __launch_bounds__(256) void pack_vt_kernel(
    const float* __restrict__ kqv, unsigned short* __restrict__ Vt)
{
    int t = blockIdx.x * 256 + threadIdx.x;        // 64*16*1024 = 1048576
    int bn = t >> 14;
    int r = (t >> 10) & 15;
    int key = t & 1023;
    int b = bn >> 3, n = bn & 7;
    unsigned short o;
    if (r < 8)      o = f2bf(kqv[(size_t)b * 393216 + 327680 + n * 8192 + key * 8 + r]);
    else if (r == 8) o = 0x3F80;                   // bf16(1.0) -> lsum row
    else            o = 0;
    Vt[(size_t)t] = o;
}

// ---------------- head-sum of q: qsum[b][s][d] = sum_n q[b][n*20480 + s*20 + d] ----
__global__ void qsum_kernel(const float* __restrict__ kqv, float* __restrict__ qsum)
{
    int idx = blockIdx.x * 256 + threadIdx.x;   // 8 * 20480 = 163840
    int b = idx / 20480, t = idx - b * 20480;
    const float* qb = kqv + (size_t)b * 393216 + 163840 + t;
    float s = 0.0f;
    #pragma unroll
    for (int n = 0; n < 8; ++n) s += qb[(size_t)n * 20480];
    qsum[idx] = s;
}

// ---------------- rel logits (relative coords), scaled by LOG2E -------------------
__global__ void rel_kernel(const float* __restrict__ qsum,
    const float* __restrict__ rel_h, const float* __restrict__ rel_w,
    float* __restrict__ Rh, float* __restrict__ Rw)
{
    int idx = blockIdx.x * 256 + threadIdx.x;   // 8 * 1024 * 63 = 516096
    int b = idx / 64512, rem = idx - b * 64512;
    int s = rem / 63, mm = rem - s * 63;
    int y = s >> 5, x = s & 31;
    const float* qrow = qsum + (size_t)b * 20480 + s * 20;
    const float* rh = rel_h + mm * 20;
    const float* rw = rel_w + mm * 20;
    float sh = 0.0f, sw = 0.0f;
    #pragma unroll
    for (int d = 0; d < 20; ++d) {
        float qv = qrow[d];
        sh += qv * rh[d];
        sw += qv * rw[d];
    }
    Rw[(size_t)b * 64512 + s * 63 + mm] = sw * LOG2E;            // [b][y*32+x][m]
    Rh[(size_t)b * 64512 + (x * 32 + y) * 63 + mm] = sh * LOG2E; // [b][x*32+y][m]
}

// ---------------- MFMA flash attention: QK^T and PV both on matrix pipe ----------
__global__ __launch_bounds__(256, 4) void attn_mfma_kernel(
    const unsigned short* __restrict__ Qb, const unsigned short* __restrict__ Kb,
    const unsigned short* __restrict__ Vt, const float* __restrict__ Rh,
    const float* __restrict__ Rw, float* __restrict__ attnout)
{
    const int bn = blockIdx.y;                    // b*8+n
    const int b = bn >> 3;
    const int i0 = blockIdx.x * 64;
    const int tid = threadIdx.x;
    const int lane = tid & 63, w = tid >> 6;

    __shared__ float RhS[64][33];
    __shared__ float RwS[64][33];
    __shared__ unsigned short Pl[4][16][72];      // per-wave P^T tile, stride 144 B
    {
        int q = tid & 63, seg = tid >> 6;
        int i = i0 + q, y1 = i >> 5, x1 = i & 31;
        const float* rh = Rh + (size_t)b * 64512 + (x1 * 32 + y1) * 63 + 31 - y1 + seg * 8;
        const float* rw = Rw + (size_t)b * 64512 + i * 63 + 31 - x1 + seg * 8;
        #pragma unroll
        for (int j = 0; j < 8; ++j) {
            RhS[q][seg * 8 + j] = rh[j];
            RwS[q][seg * 8 + j] = rw[j];
        }
    }
    __syncthreads();

    const int ql = lane & 15, g = lane >> 4;
    const int qw = i0 + w * 16;

    bf16x8 qf = *(const bf16x8*)&Qb[((size_t)bn * 1024 + qw + ql) * 32 + g * 8];
    const unsigned short* kp = Kb + ((size_t)bn * 1024 + ql) * 32 + g * 8;
    const size_t vbase = ((size_t)bn * 16 + ql) * 1024;   // lane&15 doubles as dv row

    const float* rhrow = &RhS[w * 16 + ql][0];
    float rwA[4], rwB[4];
    #pragma unroll
    for (int r = 0; r < 4; ++r) {
        rwA[r] = RwS[w * 16 + ql][4 * g + r];
        rwB[r] = RwS[w * 16 + ql][16 + 4 * g + r];
    }

    float m = -1e30f;
    f32x4 oaccT = {};                              // O^T rows g*4+r (row 8 = lsum)

    #pragma unroll 2
    for (int kt = 0; kt < 16; ++kt) {
        bf16x8 k0 = *(const bf16x8*)&kp[0 * 512];
        bf16x8 k1 = *(const bf16x8*)&kp[1 * 512];
        bf16x8 k2 = *(const bf16x8*)&kp[2 * 512];
        bf16x8 k3 = *(const bf16x8*)&kp[3 * 512];
        f32x4 s0 = {}, s1 = {}, s2 = {}, s3 = {};
        s0 = __builtin_amdgcn_mfma_f32_16x16x32_bf16(k0, qf, s0, 0, 0, 0);
        s1 = __builtin_amdgcn_mfma_f32_16x16x32_bf16(k1, qf, s1, 0, 0, 0);
        s2 = __builtin_amdgcn_mfma_f32_16x16x32_bf16(k2, qf, s2, 0, 0, 0);
        s3 = __builtin_amdgcn_mfma_f32_16x16x32_bf16(k3, qf, s3, 0, 0, 0);

        float rh0 = rhrow[2 * kt];
        float rh1 = rhrow[2 * kt + 1];
        float lg[16];
        #pragma unroll
        for (int r = 0; r < 4; ++r) {
            lg[0 + r]  = s0[r] + (rh0 + rwA[r]);
            lg[4 + r]  = s1[r] + (rh0 + rwB[r]);
            lg[8 + r]  = s2[r] + (rh1 + rwA[r]);
            lg[12 + r] = s3[r] + (rh1 + rwB[r]);
        }
        float t0 = fmaxf(fmaxf(lg[0], lg[1]), fmaxf(lg[2], lg[3]));
        float t1 = fmaxf(fmaxf(lg[4], lg[5]), fmaxf(lg[6], lg[7]));
        float t2 = fmaxf(fmaxf(lg[8], lg[9]), fmaxf(lg[10], lg[11]));
        float t3 = fmaxf(fmaxf(lg[12], lg[13]), fmaxf(lg[14], lg[15]));
        float tmax = fmaxf(fmaxf(t0, t1), fmaxf(t2, t3));
        tmax = fmaxf(tmax, __shfl_xor(tmax, 16, 64));   // query-uniform tile max
        tmax = fmaxf(tmax, __shfl_xor(tmax, 32, 64));
        float mn = fmaxf(m, tmax);
        float sc = exp2f(m - mn);
        m = mn;
        oaccT *= sc;

        // P -> bf16 -> per-wave LDS [q][key]
        #pragma unroll
        for (int jj = 0; jj < 4; ++jj) {
            float p0 = exp2f(lg[jj * 4 + 0] - mn);
            float p1 = exp2f(lg[jj * 4 + 1] - mn);
            float p2 = exp2f(lg[jj * 4 + 2] - mn);
            float p3 = exp2f(lg[jj * 4 + 3] - mn);
            int key = jj * 16 + 4 * g;
            *(unsigned*)&Pl[w][ql][key]     = cvt_pk_bf16(p0, p1);
            *(unsigned*)&Pl[w][ql][key + 2] = cvt_pk_bf16(p2, p3);
        }

        // O^T += V^T(keys) @ P^T
        #pragma unroll
        for (int half = 0; half < 2; ++half) {
            bf16x8 vfr = *(const bf16x8*)&Vt[vbase + kt * 64 + half * 32 + g * 8];
            bf16x8 pfr = *(const bf16x8*)&Pl[w][ql][half * 32 + g * 8];
            oaccT = __builtin_amdgcn_mfma_f32_16x16x32_bf16(vfr, pfr, oaccT, 0, 0, 0);
        }
        kp += 2048;                                // 64 keys * 32 elems
    }

    float lsum = __shfl(oaccT[0], 32 + ql, 64);    // row 8 lives in lane g=2, reg 0
    float inv = 1.0f / lsum;
    if (g < 2) {
        float4 o = {oaccT[0] * inv, oaccT[1] * inv, oaccT[2] * inv, oaccT[3] * inv};
        *(float4*)&attnout[((size_t)bn * 1024 + qw + ql) * 8 + g * 4] = o;
    }
}

// ---------------- attn 1x1 conv (64->64) into output channels 192..255 ------------
__global__ __launch_bounds__(256) void attn_out_conv_kernel(
    const float* __restrict__ attn, const float* __restrict__ W,
    const float* __restrict__ bias, float* __restrict__ out)
{
    const int b  = blockIdx.z;
    const int oc = blockIdx.y;
    const int s  = blockIdx.x * 256 + threadIdx.x;
    const float* ab = attn + (size_t)b * 65536;
    float sum = bias[oc];
    #pragma unroll
    for (int c = 0; c < 64; ++c)
        sum += W[oc * 64 + c] * ab[(size_t)c * 1024 + s];
    out[(size_t)b * 262144 + (size_t)(192 + oc) * 1024 + s] = sum;
}

extern "C" void kernel_launch(void* const* d_in, const int* in_sizes, int n_in,
                              void* d_out, int out_size, void* d_ws, size_t ws_size,
                              hipStream_t stream)
{
    const float* x          = (const float*)d_in[0];
    const float* kqv_w      = (const float*)d_in[1];
    const float* kqv_b      = (const float*)d_in[2];
    const float* conv_out_w = (const float*)d_in[3];
    const float* conv_out_b = (const float*)d_in[4];
    const float* attn_w     = (const float*)d_in[5];
    const float* attn_b     = (const float*)d_in[6];
    const float* rel_h      = (const float*)d_in[7];
    const float* rel_w      = (const float*)d_in[8];
    float* out = (float*)d_out;
    float* ws  = (float*)d_ws;

    float* ws_kqv  = ws;                   // 3,145,728 f32
    float* ws_qsum = ws + 3145728;         //   163,840
    float* ws_rw   = ws + 3309568;         //   516,096
    float* ws_rh   = ws + 3825664;         //   516,096
    float* ws_attn = ws + 4341760;         //   524,288
    unsigned short* Qb = (unsigned short*)(ws + 4866048);  // 2,097,152 u16 (4 MB)
    unsigned short* Kb = (unsigned short*)(ws + 5914624);  // 2,097,152 u16 (4 MB)
    unsigned short* Vt = (unsigned short*)(ws + 6963200);  // 1,048,576 u16 (2 MB)
    // total: 7,487,488 f32 = 29.95 MB

    // Transient aliases over the Qb/Kb/Vt region (dead before pack_qk/pack_vt):
    unsigned short* Xt2 = (unsigned short*)(ws + 4866048); // 2,367,488 u16 (4.73 MB)
    unsigned short* Xq  = Xt2 + 2367488;                   // 2,097,152 u16 (4.2 MB)
    unsigned short* Wp  = (unsigned short*)ws_attn;            // 884,736 B
    unsigned short* Wq  = (unsigned short*)(ws_attn + 221184); // 196,608 B

    pack_xt2_kernel  <<<1156, 256, 0, stream>>>(x, Xt2);
    pack_xq_kernel   <<<1024, 256, 0, stream>>>(x, Xq);
    pack_wconv_kernel<<< 216, 256, 0, stream>>>(conv_out_w, Wp);
    pack_wkqv_kernel <<<  48, 256, 0, stream>>>(kqv_w, Wq);
    mfma_kqv_kernel <<<dim3(16, 6, 8), 256, 0, stream>>>(Wq, Xq, kqv_b, ws_kqv);
    mfma_conv_kernel<<<dim3(16, 3, 8), 256, 0, stream>>>(Wp, Xt2, conv_out_b, out);
    pack_qk_kernel<<<512, 256, 0, stream>>>(ws_kqv, Kb, Qb);   // Xt2/Xq dead now
    pack_vt_kernel<<<4096, 256, 0, stream>>>(ws_kqv, Vt);
    qsum_kernel<<<640, 256, 0, stream>>>(ws_kqv, ws_qsum);
    rel_kernel <<<2016, 256, 0, stream>>>(ws_qsum, rel_h, rel_w, ws_rh, ws_rw);
    attn_mfma_kernel<<<dim3(16, 64), 256, 0, stream>>>(Qb, Kb, Vt, ws_rh, ws_rw, ws_attn);
    attn_out_conv_kernel<<<dim3(4, 64, 8), 256, 0, stream>>>(ws_attn, attn_w, attn_b, out);
}

// Round 8
// 112.682 us; speedup vs baseline: 5.9698x; 1.1471x over previous
//
#include <hip/hip_runtime.h>

// Problem constants: B=8, C=256, H=W=32, NH=8, DK=160, DV=64, DKH=20, DVH=8
constexpr float QSCALE = 0.22360679774997896f; // 1/sqrt(20)
constexpr float LOG2E  = 1.4426950408889634f;

typedef __attribute__((ext_vector_type(8))) short bf16x8;
typedef __attribute__((ext_vector_type(4))) float f32x4;

__device__ __forceinline__ unsigned short f2bf(float f) {
    unsigned u = __float_as_uint(f);
    u = (u + 0x7FFFu + ((u >> 16) & 1u)) >> 16;   // RNE
    return (unsigned short)u;
}

__device__ __forceinline__ unsigned cvt_pk_bf16(float lo, float hi) {
    unsigned r;
    asm("v_cvt_pk_bf16_f32 %0, %1, %2" : "=v"(r) : "v"(lo), "v"(hi));
    return r;
}

// ---- all input packs in one launch (range-dispatched) ----------------------------
// [0,295936)       : x -> Xt2 bf16 [b][chunk32(8)][spad(1156)][32ch] (halo-padded)
// [295936,558080)  : x -> Xq  bf16 fragment-order [b][g16(64)][chunk(8)][lane][8]
// [558080,613376)  : conv_out_w -> Wp fragment-order (K reordered k'=r*256+c)
// [613376,625664)  : kqv_w -> Wq fragment-order (QSCALE folded)
__global__ __launch_bounds__(256) void pack_inputs_kernel(
    const float* __restrict__ X, const float* __restrict__ Wconv,
    const float* __restrict__ Wkqv, unsigned short* __restrict__ Xt2,
    unsigned short* __restrict__ Xq, unsigned short* __restrict__ Wp,
    unsigned short* __restrict__ Wq)
{
    int t = blockIdx.x * 256 + threadIdx.x;        // 2444*256 = 625664
    if (t < 295936) {
        int b = t / 36992, rem = t - b * 36992;
        int chunk = rem / 4624; int rem2 = rem - chunk * 4624;
        int kc = rem2 / 1156;   int spad = rem2 - kc * 1156;
        int yp = spad / 34, xp = spad - yp * 34;
        bf16x8 v = {};
        if (yp >= 1 && yp <= 32 && xp >= 1 && xp <= 32) {
            const float* src = X + (size_t)b * 262144
                                 + (size_t)(chunk * 32 + kc * 8) * 1024
                                 + (yp - 1) * 32 + (xp - 1);
            #pragma unroll
            for (int j = 0; j < 8; ++j) v[j] = (short)f2bf(src[(size_t)j * 1024]);
        }
        *(bf16x8*)&Xt2[(((size_t)b * 8 + chunk) * 1156 + spad) * 32 + kc * 8] = v;
    } else if (t < 558080) {
        int t2 = t - 295936;                       // 262144
        int lane = t2 & 63;
        int chunk = (t2 >> 6) & 7;
        int g16 = (t2 >> 9) & 63;
        int b = t2 >> 15;
        int sp = g16 * 16 + (lane & 15);
        const float* src = X + (size_t)b * 262144
                             + (size_t)(chunk * 32 + (lane >> 4) * 8) * 1024 + sp;
        bf16x8 v;
        #pragma unroll
        for (int j = 0; j < 8; ++j) v[j] = (short)f2bf(src[(size_t)j * 1024]);
        *(bf16x8*)&Xq[(size_t)t2 * 8] = v;
    } else if (t < 613376) {
        int t2 = t - 558080;                       // 55296
        int l = t2 & 63;
        int rb = (t2 >> 6) & 3;
        int ks = (t2 >> 8) % 72;
        int ot = t2 / 18432;
        int oc = ot * 64 + rb * 16 + (l & 15);
        int kbase = ks * 32 + (l >> 4) * 8;
        bf16x8 v;
        #pragma unroll
        for (int j = 0; j < 8; ++j) {
            int kp = kbase + j;
            int r = kp >> 8, c = kp & 255;         // k' = r*256 + c
            v[j] = (short)f2bf(Wconv[((size_t)oc * 256 + c) * 9 + r]);
        }
        *(bf16x8*)&Wp[(size_t)t2 * 8] = v;
    } else {
        int t2 = t - 613376;                       // 12288
        int l = t2 & 63;
        int rb = (t2 >> 6) & 3;
        int ks = (t2 >> 8) & 7;
        int ot = t2 / 2048;
        int oc = ot * 64 + rb * 16 + (l & 15);
        float sc = (oc >= 160 && oc < 320) ? QSCALE : 1.0f;
        int kbase = ks * 32 + (l >> 4) * 8;
        bf16x8 v;
        #pragma unroll
        for (int j = 0; j < 8; ++j)
            v[j] = (short)f2bf(Wkqv[(size_t)oc * 256 + kbase + j] * sc);
        *(bf16x8*)&Wq[(size_t)t2 * 8] = v;
    }
}

// ---- fused GEMMs: ty 0..2 conv3x3 (LDS window, A-frags hoisted), 3..8 kqv --------
__global__ __launch_bounds__(256) void mfma_gemms_kernel(
    const unsigned short* __restrict__ Wp, const unsigned short* __restrict__ Wq,
    const unsigned short* __restrict__ Xt2, const unsigned short* __restrict__ Xq,
    const float* __restrict__ cbias, const float* __restrict__ qbias,
    float* __restrict__ out, float* __restrict__ kqv)
{
    const int b  = blockIdx.z;
    const int ty = blockIdx.y;                    // 0..8
    const int s0 = blockIdx.x * 64;
    const int tid = threadIdx.x;
    const int lane = tid & 63, w = tid >> 6;
    const int wr = w >> 1, wc = w & 1;
    const int kc = lane >> 4, ln = lane & 15;

    __shared__ unsigned short Wnd[2][136 * 36];   // conv path only

    f32x4 acc00 = {}, acc01 = {}, acc10 = {}, acc11 = {};
    const int scol = s0 + wc * 32 + ln;

    if (ty < 3) {
        // ---------------- conv path ----------------
        const int Y = blockIdx.x * 2;
        const size_t wbase = ((size_t)b * 8 * 1156 + Y * 34) * 32;
        const int f1 = tid, f2 = tid + 256, f3 = tid + 512;
        const int d1 = (f1 >> 2) * 36 + (f1 & 3) * 8;
        const int d2 = (f2 >> 2) * 36 + (f2 & 3) * 8;
        const int d3 = (f3 >> 2) * 36 + (f3 & 3) * 8;

        const size_t aoff0 = ((size_t)(ty * 288 + wr * 2) * 64 + lane) * 8;
        const size_t aoff1 = aoff0 + 512;
        const int bb = (wc * 34 + ln) * 36 + kc * 8;

        {   // prologue: stage chunk 0
            const unsigned short* g = &Xt2[wbase];
            *(bf16x8*)&Wnd[0][d1] = *(const bf16x8*)&g[f1 * 8];
            *(bf16x8*)&Wnd[0][d2] = *(const bf16x8*)&g[f2 * 8];
            if (tid < 32) *(bf16x8*)&Wnd[0][d3] = *(const bf16x8*)&g[f3 * 8];
        }
        __syncthreads();

        for (int cc = 0; cc < 8; ++cc) {
            bf16x8 v1, v2, v3;
            if (cc < 7) {                          // next chunk's stage loads early
                const unsigned short* g = &Xt2[wbase + (size_t)(cc + 1) * 1156 * 32];
                v1 = *(const bf16x8*)&g[f1 * 8];
                v2 = *(const bf16x8*)&g[f2 * 8];
                if (tid < 32) v3 = *(const bf16x8*)&g[f3 * 8];
            }
            // hoist all 18 A-fragments of this chunk into registers (ILP)
            bf16x8 A0[9], A1[9];
            #pragma unroll
            for (int r = 0; r < 9; ++r) {
                A0[r] = *(const bf16x8*)&Wp[aoff0 + (size_t)(r * 8 + cc) * 2048];
                A1[r] = *(const bf16x8*)&Wp[aoff1 + (size_t)(r * 8 + cc) * 2048];
            }

            const unsigned short* Wc = Wnd[cc & 1];
            #pragma unroll
            for (int r = 0; r < 9; ++r) {
                const int ky = r / 3, kx = r % 3;
                const int ro = (ky * 34 + kx) * 36;
                bf16x8 b0 = *(const bf16x8*)&Wc[bb + ro];
                bf16x8 b1 = *(const bf16x8*)&Wc[bb + ro + 16 * 36];
                acc00 = __builtin_amdgcn_mfma_f32_16x16x32_bf16(A0[r], b0, acc00, 0, 0, 0);
                acc01 = __builtin_amdgcn_mfma_f32_16x16x32_bf16(A0[r], b1, acc01, 0, 0, 0);
                acc10 = __builtin_amdgcn_mfma_f32_16x16x32_bf16(A1[r], b0, acc10, 0, 0, 0);
                acc11 = __builtin_amdgcn_mfma_f32_16x16x32_bf16(A1[r], b1, acc11, 0, 0, 0);
            }

            if (cc < 7) {
                unsigned short* Wn = Wnd[(cc + 1) & 1];
                *(bf16x8*)&Wn[d1] = v1;
                *(bf16x8*)&Wn[d2] = v2;
                if (tid < 32) *(bf16x8*)&Wn[d3] = v3;
            }
            __syncthreads();
        }

        const int ocb = ty * 64 + wr * 32;
        float* ob = out + (size_t)b * 262144;
        #pragma unroll
        for (int r = 0; r < 4; ++r) {
            int oc0 = ocb + kc * 4 + r;
            float b0v = cbias[oc0];
            ob[(size_t)oc0 * 1024 + scol]      = acc00[r] + b0v;
            ob[(size_t)oc0 * 1024 + scol + 16] = acc01[r] + b0v;
            int oc1 = oc0 + 16;
            float b1v = cbias[oc1];
            ob[(size_t)oc1 * 1024 + scol]      = acc10[r] + b1v;
            ob[(size_t)oc1 * 1024 + scol + 16] = acc11[r] + b1v;
        }
    } else {
        // ---------------- kqv path (LDS-free, fragment-order Xq) ----------------
        const int ot = ty - 3;                    // 0..5
        const size_t aoff0 = ((size_t)(ot * 32 + wr * 2) * 64 + lane) * 8;
        const size_t aoff1 = aoff0 + 512;
        const int g0 = blockIdx.x * 4 + wc * 2;
        const size_t xb0 = (((size_t)b * 64 + g0) * 8) * 512 + lane * 8;
        const size_t xb1 = xb0 + 4096;

        #pragma unroll
        for (int cc = 0; cc < 8; ++cc) {
            bf16x8 a0 = *(const bf16x8*)&Wq[aoff0 + (size_t)cc * 2048];
            bf16x8 a1 = *(const bf16x8*)&Wq[aoff1 + (size_t)cc * 2048];
            bf16x8 b0 = *(const bf16x8*)&Xq[xb0 + (size_t)cc * 512];
            bf16x8 b1 = *(const bf16x8*)&Xq[xb1 + (size_t)cc * 512];
            acc00 = __builtin_amdgcn_mfma_f32_16x16x32_bf16(a0, b0, acc00, 0, 0, 0);
            acc01 = __builtin_amdgcn_mfma_f32_16x16x32_bf16(a0, b1, acc01, 0, 0, 0);
            acc10 = __builtin_amdgcn_mfma_f32_16x16x32_bf16(a1, b0, acc10, 0, 0, 0);
            acc11 = __builtin_amdgcn_mfma_f32_16x16x32_bf16(a1, b1, acc11, 0, 0, 0);
        }

        const int ocb = ot * 64 + wr * 32;
        float* ob = kqv + (size_t)b * 393216;
        #pragma unroll
        for (int r = 0; r < 4; ++r) {
            int oc0 = ocb + kc * 4 + r;
            float b0v = qbias[oc0] * ((oc0 >= 160 && oc0 < 320) ? QSCALE : 1.0f);
            ob[(size_t)oc0 * 1024 + scol]      = acc00[r] + b0v;
            ob[(size_t)oc0 * 1024 + scol + 16] = acc01[r] + b0v;
            int oc1 = oc0 + 16;
            float b1v = qbias[oc1] * ((oc1 >= 160 && oc1 < 320) ? QSCALE : 1.0f);
            ob[(size_t)oc1 * 1024 + scol]      = acc10[r] + b1v;
            ob[(size_t)oc1 * 1024 + scol + 16] = acc11[r] + b1v;
        }
    }
}

// ---- pack q/k + V^T in one launch -------------------------------------------------
// [0,131072): q/k -> bf16 [bn*1024+i][32] (q scaled LOG2E)
// [131072,1179648): V -> Vt bf16 [bn][16][1024] (row 8 = ones for lsum)
__global__ __launch_bounds__(256) void pack_attn_kernel(
    const float* __restrict__ kqv, unsigned short* __restrict__ Kb,
    unsigned short* __restrict__ Qb, unsigned short* __restrict__ Vt)
{
    int idx = blockIdx.x * 256 + threadIdx.x;      // 4608*256 = 1179648
    if (idx < 131072) {
        int type = idx >> 16;                      // 0: K, 1: Q
        int r = idx & 65535;
        int bn = r >> 10, i = r & 1023;
        int b = bn >> 3, n = bn & 7;
        const float* src = kqv + (size_t)b * 393216 + (type ? 163840 : 0)
                               + n * 20480 + i * 20;
        float sc = type ? LOG2E : 1.0f;
        unsigned short* dst = (type ? Qb : Kb) + ((size_t)bn * 1024 + i) * 32;
        bf16x8 v[4] = {{}, {}, {}, {}};
        #pragma unroll
        for (int d = 0; d < 20; ++d) v[d >> 3][d & 7] = (short)f2bf(src[d] * sc);
        #pragma unroll
        for (int j = 0; j < 4; ++j) *(bf16x8*)&dst[j * 8] = v[j];
    } else {
        int t = idx - 131072;                      // 1048576
        int bn = t >> 14;
        int r = (t >> 10) & 15;
        int key = t & 1023;
        int b = bn >> 3, n = bn & 7;
        unsigned short o;
        if (r < 8)       o = f2bf(kqv[(size_t)b * 393216 + 327680 + n * 8192 + key * 8 + r]);
        else if (r == 8) o = 0x3F80;               // bf16(1.0)
        else             o = 0;
        Vt[(size_t)t] = o;
    }
}

// ---- rel logits with in-kernel head-sum (qsum pass folded in) ---------------------
// Block = (b, 16-query tile). Stages rel tables (10KB) + qsum[16][20] in LDS.
__global__ __launch_bounds__(256) void rel_kernel(
    const float* __restrict__ kqv,
    const float* __restrict__ rel_h, const float* __restrict__ rel_w,
    float* __restrict__ Rh, float* __restrict__ Rw)
{
    const int blk = blockIdx.x;                   // 8*64 = 512
    const int b = blk >> 6, st = blk & 63;
    const int s0 = st * 16;
    const int tid = threadIdx.x;
    __shared__ float rhS[63][21];
    __shared__ float rwS[63][21];
    __shared__ float qs[16][20];

    for (int i = tid; i < 1260; i += 256) {
        int mm = i / 20, d = i - mm * 20;
        rhS[mm][d] = rel_h[i];
        rwS[mm][d] = rel_w[i];
    }
    for (int e = tid; e < 320; e += 256) {
        int s = e / 20, d = e - s * 20;
        const float* qb = kqv + (size_t)b * 393216 + 163840 + (s0 + s) * 20 + d;
        float acc = 0.0f;
        #pragma unroll
        for (int n = 0; n < 8; ++n) acc += qb[(size_t)n * 20480];
        qs[s][d] = acc;
    }
    __syncthreads();

    for (int p = tid; p < 1008; p += 256) {
        int s = p / 63, mm = p - s * 63;
        float sh = 0.0f, sw = 0.0f;
        #pragma unroll
        for (int d = 0; d < 20; ++d) {
            float qv = qs[s][d];
            sh += qv * rhS[mm][d];
            sw += qv * rwS[mm][d];
        }
        int sg = s0 + s;
        int y = sg >> 5, x = sg & 31;
        Rw[(size_t)b * 64512 + sg * 63 + mm] = sw * LOG2E;
        Rh[(size_t)b * 64512 + (x * 32 + y) * 63 + mm] = sh * LOG2E;
    }
}

// ---------------- MFMA flash attention: QK^T and PV on matrix pipe ----------------
__global__ __launch_bounds__(256, 4) void attn_mfma_kernel(
    const unsigned short* __restrict__ Qb, const unsigned short* __restrict__ Kb,
    const unsigned short* __restrict__ Vt, const float* __restrict__ Rh,
    const float* __restrict__ Rw, float* __restrict__ attnout)
{
    const int bn = blockIdx.y;                    // b*8+n
    const int b = bn >> 3;
    const int i0 = blockIdx.x * 64;
    const int tid = threadIdx.x;
    const int lane = tid & 63, w = tid >> 6;

    __shared__ float RhS[64][33];
    __shared__ float RwS[64][33];
    __shared__ unsigned short Pl[4][16][72];      // per-wave P^T tile, stride 144 B
    {
        int q = tid & 63, seg = tid >> 6;
        int i = i0 + q, y1 = i >> 5, x1 = i & 31;
        const float* rh = Rh + (size_t)b * 64512 + (x1 * 32 + y1) * 63 + 31 - y1 + seg * 8;
        const float* rw = Rw + (size_t)b * 64512 + i * 63 + 31 - x1 + seg * 8;
        #pragma unroll
        for (int j = 0; j < 8; ++j) {
            RhS[q][seg * 8 + j] = rh[j];
            RwS[q][seg * 8 + j] = rw[j];
        }
    }
    __syncthreads();

    const int ql = lane & 15, g = lane >> 4;
    const int qw = i0 + w * 16;

    bf16x8 qf = *(const bf16x8*)&Qb[((size_t)bn * 1024 + qw + ql) * 32 + g * 8];
    const unsigned short* kp = Kb + ((size_t)bn * 1024 + ql) * 32 + g * 8;
    const size_t vbase = ((size_t)bn * 16 + ql) * 1024;

    const float* rhrow = &RhS[w * 16 + ql][0];
    float rwA[4], rwB[4];
    #pragma unroll
    for (int r = 0; r < 4; ++r) {
        rwA[r] = RwS[w * 16 + ql][4 * g + r];
        rwB[r] = RwS[w * 16 + ql][16 + 4 * g + r];
    }

    float m = -1e30f;
    f32x4 oaccT = {};                              // O^T rows g*4+r (row 8 = lsum)

    // K-fragment prefetch (tile 0)
    bf16x8 c0 = *(const bf16x8*)&kp[0 * 512];
    bf16x8 c1 = *(const bf16x8*)&kp[1 * 512];
    bf16x8 c2 = *(const bf16x8*)&kp[2 * 512];
    bf16x8 c3 = *(const bf16x8*)&kp[3 * 512];

    #pragma unroll 2
    for (int kt = 0; kt < 16; ++kt) {
        __builtin_amdgcn_s_setprio(1);
        f32x4 s0 = {}, s1 = {}, s2 = {}, s3 = {};
        s0 = __builtin_amdgcn_mfma_f32_16x16x32_bf16(c0, qf, s0, 0, 0, 0);
        s1 = __builtin_amdgcn_mfma_f32_16x16x32_bf16(c1, qf, s1, 0, 0, 0);
        s2 = __builtin_amdgcn_mfma_f32_16x16x32_bf16(c2, qf, s2, 0, 0, 0);
        s3 = __builtin_amdgcn_mfma_f32_16x16x32_bf16(c3, qf, s3, 0, 0, 0);
        __builtin_amdgcn_s_setprio(0);

        // issue next tile's K loads before the softmax VALU chain
        if (kt < 15) {
            kp += 2048;
            c0 = *(const bf16x8*)&kp[0 * 512];
            c1 = *(const bf16x8*)&kp[1 * 512];
            c2 = *(const bf16x8*)&kp[2 * 512];
            c3 = *(const bf16x8*)&kp[3 * 512];
        }

        float rh0 = rhrow[2 * kt];
        float rh1 = rhrow[2 * kt + 1];
        float lg[16];
        #pragma unroll
        for (int r = 0; r < 4; ++r) {
            lg[0 + r]  = s0[r] + (rh0 + rwA[r]);
            lg[4 + r]  = s1[r] + (rh0 + rwB[r]);
            lg[8 + r]  = s2[r] + (rh1 + rwA[r]);
            lg[12 + r] = s3[r] + (rh1 + rwB[r]);
        }
        float t0 = fmaxf(fmaxf(lg[0], lg[1]), fmaxf(lg[2], lg[3]));
        float t1 = fmaxf(fmaxf(lg[4], lg[5]), fmaxf(lg[6], lg[7]));
        float t2 = fmaxf(fmaxf(lg[8], lg[9]), fmaxf(lg[10], lg[11]));
        float t3 = fmaxf(fmaxf(lg[12], lg[13]), fmaxf(lg[14], lg[15]));
        float tmax = fmaxf(fmaxf(t0, t1), fmaxf(t2, t3));
        tmax = fmaxf(tmax, __shfl_xor(tmax, 16, 64));   // query-uniform tile max
        tmax = fmaxf(tmax, __shfl_xor(tmax, 32, 64));
        float mn = fmaxf(m, tmax);
        float sc = exp2f(m - mn);
        m = mn;
        oaccT *= sc;

        // P -> bf16 -> per-wave LDS [q][key]
        #pragma unroll
        for (int jj = 0; jj < 4; ++jj) {
            float p0 = exp2f(lg[jj * 4 + 0] - mn);
            float p1 = exp2f(lg[jj * 4 + 1] - mn);
            float p2 = exp2f(lg[jj * 4 + 2] - mn);
            float p3 = exp2f(lg[jj * 4 + 3] - mn);
            int key = jj * 16 + 4 * g;
            *(unsigned*)&Pl[w][ql][key]     = cvt_pk_bf16(p0, p1);
            *(unsigned*)&Pl[w][ql][key + 2] = cvt_pk_bf16(p2, p3);
        }

        // O^T += V^T(keys) @ P^T
        #pragma unroll
        for (int half = 0; half < 2; ++half) {
            bf16x8 vfr = *(const bf16x8*)&Vt[vbase + kt * 64 + half * 32 + g * 8];
            bf16x8 pfr = *(const bf16x8*)&Pl[w][ql][half * 32 + g * 8];
            __builtin_amdgcn_s_setprio(1);
            oaccT = __builtin_amdgcn_mfma_f32_16x16x32_bf16(vfr, pfr, oaccT, 0, 0, 0);
            __builtin_amdgcn_s_setprio(0);
        }
    }

    float lsum = __shfl(oaccT[0], 32 + ql, 64);    // row 8 lives in lane g=2, reg 0
    float inv = 1.0f / lsum;
    if (g < 2) {
        float4 o = {oaccT[0] * inv, oaccT[1] * inv, oaccT[2] * inv, oaccT[3] * inv};
        *(float4*)&attnout[((size_t)bn * 1024 + qw + ql) * 8 + g * 4] = o;
    }
}

// ---------------- attn 1x1 conv (64->64) into output channels 192..255 ------------
__global__ __launch_bounds__(256) void attn_out_conv_kernel(
    const float* __restrict__ attn, const float* __restrict__ W,
    const float* __restrict__ bias, float* __restrict__ out)
{
    const int b  = blockIdx.z;
    const int oc = blockIdx.y;
    const int s  = blockIdx.x * 256 + threadIdx.x;
    const float* ab = attn + (size_t)b * 65536;
    float sum = bias[oc];
    #pragma unroll
    for (int c = 0; c < 64; ++c)
        sum += W[oc * 64 + c] * ab[(size_t)c * 1024 + s];
    out[(size_t)b * 262144 + (size_t)(192 + oc) * 1024 + s] = sum;
}

extern "C" void kernel_launch(void* const* d_in, const int* in_sizes, int n_in,
                              void* d_out, int out_size, void* d_ws, size_t ws_size,
                              hipStream_t stream)
{
    const float* x          = (const float*)d_in[0];
    const float* kqv_w      = (const float*)d_in[1];
    const float* kqv_b      = (const float*)d_in[2];
    const float* conv_out_w = (const float*)d_in[3];
    const float* conv_out_b = (const float*)d_in[4];
    const float* attn_w     = (const float*)d_in[5];
    const float* attn_b     = (const float*)d_in[6];
    const float* rel_h      = (const float*)d_in[7];
    const float* rel_w      = (const float*)d_in[8];
    float* out = (float*)d_out;
    float* ws  = (float*)d_ws;

    float* ws_kqv  = ws;                   // 3,145,728 f32
    float* ws_rw   = ws + 3309568;         //   516,096
    float* ws_rh   = ws + 3825664;         //   516,096
    float* ws_attn = ws + 4341760;         //   524,288
    unsigned short* Qb = (unsigned short*)(ws + 4866048);  // 2,097,152 u16 (4 MB)
    unsigned short* Kb = (unsigned short*)(ws + 5914624);  // 2,097,152 u16 (4 MB)
    unsigned short* Vt = (unsigned short*)(ws + 6963200);  // 1,048,576 u16 (2 MB)
    // total: 7,487,488 f32 = 29.95 MB

    // Transient aliases over the Qb/Kb/Vt region (dead before pack_attn):
    unsigned short* Xt2 = (unsigned short*)(ws + 4866048); // 2,367,488 u16 (4.73 MB)
    unsigned short* Xq  = Xt2 + 2367488;                   // 2,097,152 u16 (4.2 MB)
    unsigned short* Wp  = (unsigned short*)ws_attn;            // 884,736 B
    unsigned short* Wq  = (unsigned short*)(ws_attn + 221184); // 196,608 B

    pack_inputs_kernel<<<2444, 256, 0, stream>>>(x, conv_out_w, kqv_w, Xt2, Xq, Wp, Wq);
    mfma_gemms_kernel<<<dim3(16, 9, 8), 256, 0, stream>>>(
        Wp, Wq, Xt2, Xq, conv_out_b, kqv_b, out, ws_kqv);
    pack_attn_kernel<<<4608, 256, 0, stream>>>(ws_kqv, Kb, Qb, Vt);  // Xt2/Xq dead
    rel_kernel<<<512, 256, 0, stream>>>(ws_kqv, rel_h, rel_w, ws_rh, ws_rw);
    attn_mfma_kernel<<<dim3(16, 64), 256, 0, stream>>>(Qb, Kb, Vt, ws_rh, ws_rw, ws_attn);
    attn_out_conv_kernel<<<dim3(4, 64, 8), 256, 0, stream>>>(ws_attn, attn_w, attn_b, out);
}